// Round 5
// baseline (153.184 us; speedup 1.0000x reference)
//
#include <hip/hip_runtime.h>
#include <hip/hip_bf16.h>
#include <math.h>

// Problem constants
constexpr int Bc = 2, Lc = 1024, Dc = 768, Hc = 12, dh = 64, Rc = 128;
constexpr int BL = Bc * Lc;          // 2048 tokens
constexpr int TD = 3 * Dc;           // 2304
constexpr int CH = 64;               // chunk length
constexpr int NC = Lc / CH;          // 16 chunks per sequence
constexpr int BH = Bc * Hc;          // 24

typedef __attribute__((ext_vector_type(8))) short bf16x8;
typedef __attribute__((ext_vector_type(4))) float f32x4;

__device__ __forceinline__ float bf2f(short u) {
    union { float f; unsigned int i; } c;
    c.i = ((unsigned int)(unsigned short)u) << 16;
    return c.f;
}

#define GLOAD_LDS16(gp, lp)                                                        \
    __builtin_amdgcn_global_load_lds(                                              \
        (const __attribute__((address_space(1))) void*)(gp),                       \
        (__attribute__((address_space(3))) void*)(lp), 16, 0, 0)

// ---------------- Prep: 3 weight transposes + LayerNorm, one kernel ----------------
__device__ __forceinline__ void do_transpose(const float* __restrict__ W,
                                             __hip_bfloat16* __restrict__ WT,
                                             int K, int N, int bx, int by,
                                             int tid, float* t) {
    int k0 = by * 32, n0 = bx * 32;
    int r = tid >> 5, c = tid & 31;   // r in 0..7
#pragma unroll
    for (int i = 0; i < 4; i++)
        t[(r + i * 8) * 33 + c] = W[(size_t)(k0 + r + i * 8) * N + n0 + c];
    __syncthreads();
#pragma unroll
    for (int i = 0; i < 4; i++)
        WT[(size_t)(n0 + r + i * 8) * K + k0 + c] = __float2bfloat16(t[c * 33 + r + i * 8]);
}

constexpr int NT1 = (TD / 32) * (Dc / 32);   // 1728  Wqkv
constexpr int NT2 = (Dc / 32) * (Dc / 32);   // 576   Wproj
constexpr int NT3 = (Rc / 32) * (Dc / 32);   // 96    Wb1
constexpr int NPREP = NT1 + NT2 + NT3 + BL;  // + 2048 LN rows

__global__ __launch_bounds__(256)
void prep_kernel(const float* __restrict__ x, const float* __restrict__ ln_w,
                 const float* __restrict__ ln_b,
                 const float* __restrict__ Wqkv, const float* __restrict__ Wproj,
                 const float* __restrict__ Wb1,
                 __hip_bfloat16* __restrict__ xnb, __hip_bfloat16* __restrict__ xb,
                 __hip_bfloat16* __restrict__ WqkvT, __hip_bfloat16* __restrict__ WprojT,
                 __hip_bfloat16* __restrict__ Wb1T) {
    __shared__ float shm[32 * 33];
    int bid = blockIdx.x, tid = threadIdx.x;
    if (bid < NT1) { do_transpose(Wqkv, WqkvT, Dc, TD, bid % 72, bid / 72, tid, shm); return; }
    bid -= NT1;
    if (bid < NT2) { do_transpose(Wproj, WprojT, Dc, Dc, bid % 24, bid / 24, tid, shm); return; }
    bid -= NT2;
    if (bid < NT3) { do_transpose(Wb1, Wb1T, Dc, Rc, bid % 4, bid / 4, tid, shm); return; }
    bid -= NT3;
    // LayerNorm row
    int row = bid;
    const float* xr = x + (size_t)row * Dc;
    __hip_bfloat16* yr = xnb + (size_t)row * Dc;
    __hip_bfloat16* xbr = xb + (size_t)row * Dc;
    float v[3];
    float s = 0.f;
#pragma unroll
    for (int i = 0; i < 3; i++) { v[i] = xr[tid + i * 256]; s += v[i]; }
    shm[tid] = s; __syncthreads();
    for (int off = 128; off > 0; off >>= 1) {
        if (tid < off) shm[tid] += shm[tid + off];
        __syncthreads();
    }
    float mu = shm[0] / (float)Dc;
    __syncthreads();
    float s2 = 0.f;
#pragma unroll
    for (int i = 0; i < 3; i++) { float d = v[i] - mu; s2 += d * d; }
    shm[tid] = s2; __syncthreads();
    for (int off = 128; off > 0; off >>= 1) {
        if (tid < off) shm[tid] += shm[tid + off];
        __syncthreads();
    }
    float rstd = rsqrtf(shm[0] / (float)Dc + 1e-5f);
#pragma unroll
    for (int i = 0; i < 3; i++) {
        int c = tid + i * 256;
        yr[c] = __float2bfloat16((v[i] - mu) * rstd * ln_w[c] + ln_b[c]);
        xbr[c] = __float2bfloat16(v[i]);
    }
}

// ---------------- bf16 MFMA GEMM, 2-phase global_load_lds pipeline ----------------
template <bool OUT_BF16, int ACT>
__global__ __launch_bounds__(512)
void gemm_mfma_kernel(const __hip_bfloat16* __restrict__ A,
                      const __hip_bfloat16* __restrict__ BT,
                      const float* __restrict__ bias,
                      void* __restrict__ Cout, int M, int N, int K) {
    __shared__ short lds[2][2][128 * 64];   // [buf][A/B][row*64 + elem]
    int tid = threadIdx.x;
    int wave = tid >> 6, lane = tid & 63;
    int l16 = lane & 15, l4 = lane >> 4;
    int m0 = blockIdx.y * 128, n0 = blockIdx.x * 128;

    int ab = wave >> 2;                       // 0 = A, 1 = B
    int r_in = lane >> 3;                     // 0..7 row within 8-row group
    int s_src = (lane & 7) ^ r_in;            // inverse-swizzled source slot
    const __hip_bfloat16* gbase = ab ? (BT + (size_t)n0 * K) : (A + (size_t)m0 * K);
    const __hip_bfloat16* gsrc =
        gbase + (size_t)((wave & 3) * 32 + r_in) * K + s_src * 8;

    int wr = (wave >> 2) * 64, wc = (wave & 3) * 32;
    int xs = l16 & 7;                         // read-side XOR (== row & 7)

    f32x4 acc[4][2];
#pragma unroll
    for (int i = 0; i < 4; i++)
#pragma unroll
        for (int j = 0; j < 2; j++) acc[i][j] = f32x4{0.f, 0.f, 0.f, 0.f};

    auto stage = [&](int buf, int kt) {
        const __hip_bfloat16* g = gsrc + kt * 64;
        short* lb = &lds[buf][ab][(wave & 3) * 32 * 64];
#pragma unroll
        for (int i = 0; i < 4; i++)
            GLOAD_LDS16(g + (size_t)i * 8 * K, lb + i * 8 * 64);
    };

    auto compute = [&](int buf) {
        const short* As = &lds[buf][0][0];
        const short* Bs = &lds[buf][1][0];
#pragma unroll
        for (int kk = 0; kk < 2; kk++) {
            bf16x8 af[4], bfr[2];
            int slot = (kk * 4 + l4) ^ xs;
#pragma unroll
            for (int f = 0; f < 4; f++)
                af[f] = *reinterpret_cast<const bf16x8*>(
                    &As[(wr + f * 16 + l16) * 64 + slot * 8]);
#pragma unroll
            for (int f = 0; f < 2; f++)
                bfr[f] = *reinterpret_cast<const bf16x8*>(
                    &Bs[(wc + f * 16 + l16) * 64 + slot * 8]);
#pragma unroll
            for (int i = 0; i < 4; i++)
#pragma unroll
                for (int j = 0; j < 2; j++)
                    acc[i][j] = __builtin_amdgcn_mfma_f32_16x16x32_bf16(
                        af[i], bfr[j], acc[i][j], 0, 0, 0);
        }
    };

    int NT = K / 64;
    int cur = 0;
    stage(0, 0);
    __syncthreads();
    for (int t = 0; t < NT; t++) {
        if (t + 1 < NT) stage(cur ^ 1, t + 1);
        compute(cur);
        if (t + 1 < NT) { __syncthreads(); cur ^= 1; }
    }

    int crow = l4 * 4;
#pragma unroll
    for (int i = 0; i < 4; i++) {
#pragma unroll
        for (int j = 0; j < 2; j++) {
            int col = n0 + wc + j * 16 + l16;
            float bb = bias ? bias[col] : 0.f;
#pragma unroll
            for (int r = 0; r < 4; r++) {
                int rowm = m0 + wr + i * 16 + crow + r;
                float v = acc[i][j][r] + bb;
                if (ACT == 1) v = v / (1.f + expf(-v));
                if (OUT_BF16)
                    ((__hip_bfloat16*)Cout)[(size_t)rowm * N + col] = __float2bfloat16(v);
                else
                    ((float*)Cout)[(size_t)rowm * N + col] = v;
            }
        }
    }
}

// ---------------- Gate params ----------------
__global__ __launch_bounds__(256)
void gate_kernel(const float* __restrict__ tbuf, const float* __restrict__ Wb2,
                 const float* __restrict__ temperature,
                 float* __restrict__ gate_out, float* __restrict__ og) {
    int id = blockIdx.x * 256 + threadIdx.x;   // < 24576
    int tok = id / Hc, h = id % Hc;
    const float* tr = tbuf + (size_t)tok * Rc;
    float p[5] = {};
    for (int r = 0; r < Rc; r++) {
        float tv = tr[r];
        const float* wr = Wb2 + r * (Hc * 5) + h * 5;
#pragma unroll
        for (int c = 0; c < 5; c++) p[c] = fmaf(tv, wr[c], p[c]);
    }
    const float PI = 3.14159265358979323846f;
    float sem_amp = 1.f / (1.f + expf(-p[0]));
    float sem_phase = tanhf(p[1]) * PI;
    float ctx_amp = 1.f / (1.f + expf(-p[2]));
    float ctx_phase = tanhf(p[3]) * PI;
    float temp = fminf(fmaxf(temperature[0], 0.1f), 2.0f);
    float inter = tanhf(sem_amp * ctx_amp * cosf(sem_phase - ctx_phase)) * temp;
    float g = 1.f / (1.f + expf(-inter));
    gate_out[id] = g;
    og[id] = 1.f + g;
}

// ---------------- Phase A: per-chunk U_c = K^T diag(1+g) V (RAW, no prefix), zc ----------------
__global__ __launch_bounds__(256)
void phaseA_kernel(const __hip_bfloat16* __restrict__ qkv, const float* __restrict__ og,
                   float* __restrict__ SU, float* __restrict__ zc) {
    int bid = blockIdx.x;           // bh*16 + c
    int bh = bid >> 4, c = bid & 15;
    int b = bh / Hc, h = bh % Hc;
    int tok0 = b * Lc + c * CH;
    __shared__ float Ks[64 * 64];
    __shared__ float Vs[64 * 64];
    int tid = threadIdx.x;
#pragma unroll
    for (int i = 0; i < 2; i++) {
        int c8 = tid + i * 256;
        int tt = c8 >> 3, d8 = (c8 & 7) * 8;
        size_t rowoff = (size_t)(tok0 + tt) * TD + h * dh;
        bf16x8 k8 = *reinterpret_cast<const bf16x8*>(qkv + rowoff + Dc + d8);
        bf16x8 v8 = *reinterpret_cast<const bf16x8*>(qkv + rowoff + 2 * Dc + d8);
        float gv = og[(size_t)(tok0 + tt) * Hc + h];
        float kf[8], vf[8];
#pragma unroll
        for (int j = 0; j < 8; j++) {
            float kv = bf2f(k8[j]);
            kf[j] = kv > 0.f ? kv + 1.f : expf(kv);
            vf[j] = bf2f(v8[j]) * gv;
        }
        *reinterpret_cast<float4*>(&Ks[tt * 64 + d8])     = *reinterpret_cast<float4*>(&kf[0]);
        *reinterpret_cast<float4*>(&Ks[tt * 64 + d8 + 4]) = *reinterpret_cast<float4*>(&kf[4]);
        *reinterpret_cast<float4*>(&Vs[tt * 64 + d8])     = *reinterpret_cast<float4*>(&vf[0]);
        *reinterpret_cast<float4*>(&Vs[tt * 64 + d8 + 4]) = *reinterpret_cast<float4*>(&vf[4]);
    }
    __syncthreads();
    int e = tid & 63, d0 = (tid >> 6) * 16;
    float u[16] = {};
    for (int tt = 0; tt < 64; tt++) {
        float vv = Vs[tt * 64 + e];
        float4 k4[4];
#pragma unroll
        for (int q = 0; q < 4; q++)
            k4[q] = *reinterpret_cast<const float4*>(&Ks[tt * 64 + d0 + q * 4]);
        const float* kk = reinterpret_cast<const float*>(k4);
#pragma unroll
        for (int j = 0; j < 16; j++)
            u[j] = fmaf(kk[j], vv, u[j]);
    }
    float* Uo = SU + (size_t)bid * 4096;
#pragma unroll
    for (int j = 0; j < 16; j++)
        Uo[(d0 + j) * 64 + e] = u[j];
    if (tid < 64) {
        float zsum = 0.f;
        for (int tt = 0; tt < 64; tt++) zsum += Ks[tt * 64 + tid];
        zc[bid * 64 + tid] = zsum;
    }
}

// ---------------- Phase C: inline prefix + per-chunk output + mini-LN, bf16 out ----------------
__global__ __launch_bounds__(256)
void phaseC_kernel(const __hip_bfloat16* __restrict__ qkv, const float* __restrict__ og,
                   const float* __restrict__ SU, const float* __restrict__ zc,
                   const float* __restrict__ mn_w, const float* __restrict__ mn_b,
                   __hip_bfloat16* __restrict__ attn) {
    int bid = blockIdx.x;           // bh*16 + c
    int bh = bid >> 4, c = bid & 15;
    int b = bh / Hc, h = bh % Hc;
    int tok0 = b * Lc + c * CH;
    __shared__ float Qs[64 * 65];
    __shared__ float As[64 * 65];
    __shared__ float Ks[64 * 64];   // step 1: k_f; after barrier2: S_start
    __shared__ float Vs[64 * 64];
    __shared__ float zs[64];
    __shared__ float dens[64];
    __shared__ float denp[4][64];   // den partials; reused as LN sum partials
    __shared__ float sqp[4][64];    // LN sum-sq partials
    int tid = threadIdx.x;
    int lane = tid & 63, grp = tid >> 6;

    // z_start (exclusive prefix of chunk z-sums) — global reads, pre-barrier
    if (tid < 64) {
        const float* zcb = zc + (size_t)bh * NC * 64;
        float s = 0.f;
        for (int cc = 0; cc < c; cc++) s += zcb[cc * 64 + tid];
        zs[tid] = s;
    }
#pragma unroll
    for (int i = 0; i < 2; i++) {
        int c8 = tid + i * 256;
        int tt = c8 >> 3, d8 = (c8 & 7) * 8;
        size_t rowoff = (size_t)(tok0 + tt) * TD + h * dh;
        bf16x8 q8 = *reinterpret_cast<const bf16x8*>(qkv + rowoff + d8);
        bf16x8 k8 = *reinterpret_cast<const bf16x8*>(qkv + rowoff + Dc + d8);
        bf16x8 v8 = *reinterpret_cast<const bf16x8*>(qkv + rowoff + 2 * Dc + d8);
        float gv = og[(size_t)(tok0 + tt) * Hc + h];
        float kf[8], vf[8];
#pragma unroll
        for (int j = 0; j < 8; j++) {
            float qv = bf2f(q8[j]);
            Qs[tt * 65 + d8 + j] = qv > 0.f ? qv + 1.f : expf(qv);
            float kv = bf2f(k8[j]);
            kf[j] = kv > 0.f ? kv + 1.f : expf(kv);
            vf[j] = bf2f(v8[j]) * gv;
        }
        *reinterpret_cast<float4*>(&Ks[tt * 64 + d8])     = *reinterpret_cast<float4*>(&kf[0]);
        *reinterpret_cast<float4*>(&Ks[tt * 64 + d8 + 4]) = *reinterpret_cast<float4*>(&kf[4]);
        *reinterpret_cast<float4*>(&Vs[tt * 64 + d8])     = *reinterpret_cast<float4*>(&vf[0]);
        *reinterpret_cast<float4*>(&Vs[tt * 64 + d8 + 4]) = *reinterpret_cast<float4*>(&vf[4]);
    }
    __syncthreads();   // barrier 1

    // Step 1: masked dots. thread = (l=lane, t in [grp*16, grp*16+16))
    int t0 = grp * 16;
    float dotp[16] = {};
    for (int dc = 0; dc < 64; dc += 4) {
        float q0 = Qs[lane * 65 + dc];
        float q1 = Qs[lane * 65 + dc + 1];
        float q2 = Qs[lane * 65 + dc + 2];
        float q3 = Qs[lane * 65 + dc + 3];
#pragma unroll
        for (int j = 0; j < 16; j++) {
            float4 k4 = *reinterpret_cast<const float4*>(&Ks[(t0 + j) * 64 + dc]);
            dotp[j] = fmaf(q0, k4.x, fmaf(q1, k4.y, fmaf(q2, k4.z, fmaf(q3, k4.w, dotp[j]))));
        }
    }
    float dsum = 0.f;
#pragma unroll
    for (int j = 0; j < 16; j++) {
        float dv = (t0 + j) <= lane ? dotp[j] : 0.f;
        As[lane * 65 + t0 + j] = dv;
        dsum += dv;
    }
    denp[grp][lane] = dsum;
    __syncthreads();   // barrier 2

    // den[l]; in parallel, build S_start into Ks
    if (tid < 64) {
        int l = tid;
        float qz = 0.f;
        for (int dc = 0; dc < 64; dc += 4) {
            float4 z4 = *reinterpret_cast<const float4*>(&zs[dc]);
            qz = fmaf(Qs[l * 65 + dc], z4.x,
                 fmaf(Qs[l * 65 + dc + 1], z4.y,
                 fmaf(Qs[l * 65 + dc + 2], z4.z,
                 fmaf(Qs[l * 65 + dc + 3], z4.w, qz))));
        }
        dens[l] = denp[0][l] + denp[1][l] + denp[2][l] + denp[3][l] + qz + 1e-6f;
    }
    {
        const float* SUb = SU + (size_t)bh * NC * 4096;
        for (int i = tid; i < 4096; i += 256) {
            float s = 0.f;
            for (int cc = 0; cc < c; cc++) s += SUb[cc * 4096 + i];
            Ks[i] = s;     // Ks now holds S_start [d][e]
        }
    }
    __syncthreads();   // barrier 3

    // Step 2: out_num[l][e] ; thread = (l=lane, e in [grp*16, grp*16+16))
    int e0 = grp * 16;
    float acc[16] = {};
    for (int d = 0; d < 64; d++) {
        float qv = Qs[lane * 65 + d];
#pragma unroll
        for (int jc = 0; jc < 4; jc++) {
            float4 s4 = *reinterpret_cast<const float4*>(&Ks[d * 64 + e0 + jc * 4]);
            acc[jc * 4 + 0] = fmaf(qv, s4.x, acc[jc * 4 + 0]);
            acc[jc * 4 + 1] = fmaf(qv, s4.y, acc[jc * 4 + 1]);
            acc[jc * 4 + 2] = fmaf(qv, s4.z, acc[jc * 4 + 2]);
            acc[jc * 4 + 3] = fmaf(qv, s4.w, acc[jc * 4 + 3]);
        }
    }
    for (int t = 0; t < 64; t++) {
        float av = As[lane * 65 + t];
#pragma unroll
        for (int jc = 0; jc < 4; jc++) {
            float4 v4 = *reinterpret_cast<const float4*>(&Vs[t * 64 + e0 + jc * 4]);
            acc[jc * 4 + 0] = fmaf(av, v4.x, acc[jc * 4 + 0]);
            acc[jc * 4 + 1] = fmaf(av, v4.y, acc[jc * 4 + 1]);
            acc[jc * 4 + 2] = fmaf(av, v4.z, acc[jc * 4 + 2]);
            acc[jc * 4 + 3] = fmaf(av, v4.w, acc[jc * 4 + 3]);
        }
    }

    // divide by den; LN partials over e (4 grp-threads per row l)
    float invden = 1.f / dens[lane];
    float val[16];
    float s1 = 0.f, s2 = 0.f;
#pragma unroll
    for (int j = 0; j < 16; j++) {
        val[j] = acc[j] * invden;
        s1 += val[j];
        s2 += val[j] * val[j];
    }
    denp[grp][lane] = s1;
    sqp[grp][lane] = s2;
    __syncthreads();   // barrier 4
    float mu = (denp[0][lane] + denp[1][lane] + denp[2][lane] + denp[3][lane]) * (1.f / 64.f);
    float ex2 = (sqp[0][lane] + sqp[1][lane] + sqp[2][lane] + sqp[3][lane]) * (1.f / 64.f);
    float rstd = rsqrtf(ex2 - mu * mu + 1e-5f);

    union { __hip_bfloat16 b[16]; uint4 v4[2]; } ob;
#pragma unroll
    for (int jc = 0; jc < 4; jc++) {
        float4 w4 = *reinterpret_cast<const float4*>(&mn_w[e0 + jc * 4]);
        float4 b4 = *reinterpret_cast<const float4*>(&mn_b[e0 + jc * 4]);
        ob.b[jc * 4 + 0] = __float2bfloat16((val[jc * 4 + 0] - mu) * rstd * w4.x + b4.x);
        ob.b[jc * 4 + 1] = __float2bfloat16((val[jc * 4 + 1] - mu) * rstd * w4.y + b4.y);
        ob.b[jc * 4 + 2] = __float2bfloat16((val[jc * 4 + 2] - mu) * rstd * w4.z + b4.z);
        ob.b[jc * 4 + 3] = __float2bfloat16((val[jc * 4 + 3] - mu) * rstd * w4.w + b4.w);
    }
    uint4* outp = reinterpret_cast<uint4*>(attn + (size_t)(tok0 + lane) * Dc + h * dh + e0);
    outp[0] = ob.v4[0];
    outp[1] = ob.v4[1];
}

extern "C" void kernel_launch(void* const* d_in, const int* in_sizes, int n_in,
                              void* d_out, int out_size, void* d_ws, size_t ws_size,
                              hipStream_t stream) {
    const float* x     = (const float*)d_in[0];
    const float* Wqkv  = (const float*)d_in[1];
    const float* bqkv  = (const float*)d_in[2];
    const float* Wb1   = (const float*)d_in[3];
    const float* Wb2   = (const float*)d_in[4];
    const float* temp  = (const float*)d_in[5];
    const float* Wproj = (const float*)d_in[6];
    const float* bproj = (const float*)d_in[7];
    const float* ln_w  = (const float*)d_in[8];
    const float* ln_b  = (const float*)d_in[9];
    const float* mn_w  = (const float*)d_in[10];
    const float* mn_b  = (const float*)d_in[11];

    float* out0 = (float*)d_out;                 // [2048, 768]
    float* gate = out0 + (size_t)BL * Dc;        // [2048, 12]

    float* ws   = (float*)d_ws;
    float* tbuf = ws;                            // 2048*128 f32
    float* og   = tbuf + (size_t)BL * Rc;        // 2048*12 f32
    float* SU   = og + (size_t)BL * Hc;          // 24*16*4096 f32 (raw U_c)
    float* zc   = SU + (size_t)BH * NC * 4096;   // 24*16*64 f32 (raw z sums)
    __hip_bfloat16* bfr = (__hip_bfloat16*)(zc + (size_t)BH * NC * 64);
    __hip_bfloat16* qkvb   = bfr;                        // 2048*2304 bf16
    __hip_bfloat16* xnb    = qkvb + (size_t)BL * TD;     // 2048*768 bf16
    __hip_bfloat16* xb     = xnb + (size_t)BL * Dc;      // 2048*768 bf16 (raw x)
    __hip_bfloat16* attnb  = xb + (size_t)BL * Dc;       // 2048*768 bf16
    __hip_bfloat16* WqkvT  = attnb + (size_t)BL * Dc;    // 2304*768 bf16
    __hip_bfloat16* WprojT = WqkvT + (size_t)TD * Dc;    // 768*768 bf16
    __hip_bfloat16* Wb1T   = WprojT + (size_t)Dc * Dc;   // 128*768 bf16

    // 1. prep: weight transposes + LayerNorm
    prep_kernel<<<NPREP, 256, 0, stream>>>(x, ln_w, ln_b, Wqkv, Wproj, Wb1,
                                           xnb, xb, WqkvT, WprojT, Wb1T);
    // 2. qkv = x_norm @ Wqkv + bqkv   (bf16 MFMA, bf16 out)
    gemm_mfma_kernel<true, 0><<<dim3(TD / 128, BL / 128), 512, 0, stream>>>(
        xnb, WqkvT, bqkv, qkvb, BL, TD, Dc);
    // 3. t = silu(x @ Wb1)   (raw x, bf16 MFMA, fp32 out)
    gemm_mfma_kernel<false, 1><<<dim3(Rc / 128, BL / 128), 512, 0, stream>>>(
        xb, Wb1T, nullptr, tbuf, BL, Rc, Dc);
    // 4. gate + (1+gate)
    gate_kernel<<<BL * Hc / 256, 256, 0, stream>>>(tbuf, Wb2, temp, gate, og);
    // 5. per-chunk local KV state sums (raw)
    phaseA_kernel<<<BH * NC, 256, 0, stream>>>(qkvb, og, SU, zc);
    // 6. per-chunk outputs (inline prefix) + mini-LN -> bf16
    phaseC_kernel<<<BH * NC, 256, 0, stream>>>(qkvb, og, SU, zc, mn_w, mn_b, attnb);
    // 7. out0 = attn @ Wproj + bproj  (bf16 MFMA, fp32 out)
    gemm_mfma_kernel<false, 0><<<dim3(Dc / 128, BL / 128), 512, 0, stream>>>(
        attnb, WprojT, bproj, out0, BL, Dc, Dc);
}

// Round 6
// 83.432 us; speedup vs baseline: 1.8360x; 1.8360x over previous
//
#include <hip/hip_runtime.h>
#include <hip/hip_bf16.h>
#include <math.h>

// Problem constants
constexpr int Bc = 2, Lc = 1024, Dc = 768, Hc = 12, dh = 64, Rc = 128;
constexpr int BL = Bc * Lc;          // 2048 tokens
constexpr int TD = 3 * Dc;           // 2304
constexpr int CH = 64;               // chunk length
constexpr int NC = Lc / CH;          // 16 chunks per sequence
constexpr int BH = Bc * Hc;          // 24

typedef __attribute__((ext_vector_type(8))) short bf16x8;
typedef __attribute__((ext_vector_type(4))) float f32x4;

__device__ __forceinline__ float bf2f(short u) {
    union { float f; unsigned int i; } c;
    c.i = ((unsigned int)(unsigned short)u) << 16;
    return c.f;
}
__device__ __forceinline__ short f2b(float f) {
    __hip_bfloat16 h = __float2bfloat16(f);
    return *reinterpret_cast<short*>(&h);
}

#define GLOAD_LDS16(gp, lp)                                                        \
    __builtin_amdgcn_global_load_lds(                                              \
        (const __attribute__((address_space(1))) void*)(gp),                       \
        (__attribute__((address_space(3))) void*)(lp), 16, 0, 0)

// ---------------- Prep: 3 weight transposes + LayerNorm, one kernel ----------------
__device__ __forceinline__ void do_transpose(const float* __restrict__ W,
                                             __hip_bfloat16* __restrict__ WT,
                                             int K, int N, int bx, int by,
                                             int tid, float* t) {
    int k0 = by * 32, n0 = bx * 32;
    int r = tid >> 5, c = tid & 31;   // r in 0..7
#pragma unroll
    for (int i = 0; i < 4; i++)
        t[(r + i * 8) * 33 + c] = W[(size_t)(k0 + r + i * 8) * N + n0 + c];
    __syncthreads();
#pragma unroll
    for (int i = 0; i < 4; i++)
        WT[(size_t)(n0 + r + i * 8) * K + k0 + c] = __float2bfloat16(t[c * 33 + r + i * 8]);
}

constexpr int NT1 = (TD / 32) * (Dc / 32);   // 1728  Wqkv
constexpr int NT2 = (Dc / 32) * (Dc / 32);   // 576   Wproj
constexpr int NT3 = (Rc / 32) * (Dc / 32);   // 96    Wb1
constexpr int NPREP = NT1 + NT2 + NT3 + BL;  // + 2048 LN rows

__global__ __launch_bounds__(256)
void prep_kernel(const float* __restrict__ x, const float* __restrict__ ln_w,
                 const float* __restrict__ ln_b,
                 const float* __restrict__ Wqkv, const float* __restrict__ Wproj,
                 const float* __restrict__ Wb1,
                 __hip_bfloat16* __restrict__ xnb, __hip_bfloat16* __restrict__ xb,
                 __hip_bfloat16* __restrict__ WqkvT, __hip_bfloat16* __restrict__ WprojT,
                 __hip_bfloat16* __restrict__ Wb1T) {
    __shared__ float shm[32 * 33];
    int bid = blockIdx.x, tid = threadIdx.x;
    if (bid < NT1) { do_transpose(Wqkv, WqkvT, Dc, TD, bid % 72, bid / 72, tid, shm); return; }
    bid -= NT1;
    if (bid < NT2) { do_transpose(Wproj, WprojT, Dc, Dc, bid % 24, bid / 24, tid, shm); return; }
    bid -= NT2;
    if (bid < NT3) { do_transpose(Wb1, Wb1T, Dc, Rc, bid % 4, bid / 4, tid, shm); return; }
    bid -= NT3;
    // LayerNorm row
    int row = bid;
    const float* xr = x + (size_t)row * Dc;
    __hip_bfloat16* yr = xnb + (size_t)row * Dc;
    __hip_bfloat16* xbr = xb + (size_t)row * Dc;
    float v[3];
    float s = 0.f;
#pragma unroll
    for (int i = 0; i < 3; i++) { v[i] = xr[tid + i * 256]; s += v[i]; }
    shm[tid] = s; __syncthreads();
    for (int off = 128; off > 0; off >>= 1) {
        if (tid < off) shm[tid] += shm[tid + off];
        __syncthreads();
    }
    float mu = shm[0] / (float)Dc;
    __syncthreads();
    float s2 = 0.f;
#pragma unroll
    for (int i = 0; i < 3; i++) { float d = v[i] - mu; s2 += d * d; }
    shm[tid] = s2; __syncthreads();
    for (int off = 128; off > 0; off >>= 1) {
        if (tid < off) shm[tid] += shm[tid + off];
        __syncthreads();
    }
    float rstd = rsqrtf(shm[0] / (float)Dc + 1e-5f);
#pragma unroll
    for (int i = 0; i < 3; i++) {
        int c = tid + i * 256;
        yr[c] = __float2bfloat16((v[i] - mu) * rstd * ln_w[c] + ln_b[c]);
        xbr[c] = __float2bfloat16(v[i]);
    }
}

// ---------------- bf16 MFMA GEMM, 2-phase global_load_lds pipeline ----------------
template <bool OUT_BF16, int ACT>
__global__ __launch_bounds__(512)
void gemm_mfma_kernel(const __hip_bfloat16* __restrict__ A,
                      const __hip_bfloat16* __restrict__ BT,
                      const float* __restrict__ bias,
                      void* __restrict__ Cout, int M, int N, int K) {
    __shared__ short lds[2][2][128 * 64];   // [buf][A/B][row*64 + elem]
    int tid = threadIdx.x;
    int wave = tid >> 6, lane = tid & 63;
    int l16 = lane & 15, l4 = lane >> 4;
    int m0 = blockIdx.y * 128, n0 = blockIdx.x * 128;

    int ab = wave >> 2;                       // 0 = A, 1 = B
    int r_in = lane >> 3;                     // 0..7 row within 8-row group
    int s_src = (lane & 7) ^ r_in;            // inverse-swizzled source slot
    const __hip_bfloat16* gbase = ab ? (BT + (size_t)n0 * K) : (A + (size_t)m0 * K);
    const __hip_bfloat16* gsrc =
        gbase + (size_t)((wave & 3) * 32 + r_in) * K + s_src * 8;

    int wr = (wave >> 2) * 64, wc = (wave & 3) * 32;
    int xs = l16 & 7;                         // read-side XOR (== row & 7)

    f32x4 acc[4][2];
#pragma unroll
    for (int i = 0; i < 4; i++)
#pragma unroll
        for (int j = 0; j < 2; j++) acc[i][j] = f32x4{0.f, 0.f, 0.f, 0.f};

    auto stage = [&](int buf, int kt) {
        const __hip_bfloat16* g = gsrc + kt * 64;
        short* lb = &lds[buf][ab][(wave & 3) * 32 * 64];
#pragma unroll
        for (int i = 0; i < 4; i++)
            GLOAD_LDS16(g + (size_t)i * 8 * K, lb + i * 8 * 64);
    };

    auto compute = [&](int buf) {
        const short* As = &lds[buf][0][0];
        const short* Bs = &lds[buf][1][0];
#pragma unroll
        for (int kk = 0; kk < 2; kk++) {
            bf16x8 af[4], bfr[2];
            int slot = (kk * 4 + l4) ^ xs;
#pragma unroll
            for (int f = 0; f < 4; f++)
                af[f] = *reinterpret_cast<const bf16x8*>(
                    &As[(wr + f * 16 + l16) * 64 + slot * 8]);
#pragma unroll
            for (int f = 0; f < 2; f++)
                bfr[f] = *reinterpret_cast<const bf16x8*>(
                    &Bs[(wc + f * 16 + l16) * 64 + slot * 8]);
#pragma unroll
            for (int i = 0; i < 4; i++)
#pragma unroll
                for (int j = 0; j < 2; j++)
                    acc[i][j] = __builtin_amdgcn_mfma_f32_16x16x32_bf16(
                        af[i], bfr[j], acc[i][j], 0, 0, 0);
        }
    };

    int NT = K / 64;
    int cur = 0;
    stage(0, 0);
    __syncthreads();
    for (int t = 0; t < NT; t++) {
        if (t + 1 < NT) stage(cur ^ 1, t + 1);
        compute(cur);
        if (t + 1 < NT) { __syncthreads(); cur ^= 1; }
    }

    int crow = l4 * 4;
#pragma unroll
    for (int i = 0; i < 4; i++) {
#pragma unroll
        for (int j = 0; j < 2; j++) {
            int col = n0 + wc + j * 16 + l16;
            float bb = bias ? bias[col] : 0.f;
#pragma unroll
            for (int r = 0; r < 4; r++) {
                int rowm = m0 + wr + i * 16 + crow + r;
                float v = acc[i][j][r] + bb;
                if (ACT == 1) v = v / (1.f + expf(-v));
                if (OUT_BF16)
                    ((__hip_bfloat16*)Cout)[(size_t)rowm * N + col] = __float2bfloat16(v);
                else
                    ((float*)Cout)[(size_t)rowm * N + col] = v;
            }
        }
    }
}

// ---------------- Gate params ----------------
__global__ __launch_bounds__(256)
void gate_kernel(const float* __restrict__ tbuf, const float* __restrict__ Wb2,
                 const float* __restrict__ temperature,
                 float* __restrict__ gate_out, float* __restrict__ og) {
    int id = blockIdx.x * 256 + threadIdx.x;   // < 24576
    int tok = id / Hc, h = id % Hc;
    const float* tr = tbuf + (size_t)tok * Rc;
    float p[5] = {};
    for (int r = 0; r < Rc; r++) {
        float tv = tr[r];
        const float* wr = Wb2 + r * (Hc * 5) + h * 5;
#pragma unroll
        for (int c = 0; c < 5; c++) p[c] = fmaf(tv, wr[c], p[c]);
    }
    const float PI = 3.14159265358979323846f;
    float sem_amp = 1.f / (1.f + expf(-p[0]));
    float sem_phase = tanhf(p[1]) * PI;
    float ctx_amp = 1.f / (1.f + expf(-p[2]));
    float ctx_phase = tanhf(p[3]) * PI;
    float temp = fminf(fmaxf(temperature[0], 0.1f), 2.0f);
    float inter = tanhf(sem_amp * ctx_amp * cosf(sem_phase - ctx_phase)) * temp;
    float g = 1.f / (1.f + expf(-inter));
    gate_out[id] = g;
    og[id] = 1.f + g;
}

// ---------------- Phase A: per-chunk U_c^T (stored [e][d]), zc = sum K ----------------
__global__ __launch_bounds__(256)
void phaseA_kernel(const __hip_bfloat16* __restrict__ qkv, const float* __restrict__ og,
                   float* __restrict__ SU, float* __restrict__ zc) {
    int bid = blockIdx.x;           // bh*16 + c
    int bh = bid >> 4, c = bid & 15;
    int b = bh / Hc, h = bh % Hc;
    int tok0 = b * Lc + c * CH;
    __shared__ float Ks[64 * 64];
    __shared__ float Vs[64 * 64];
    int tid = threadIdx.x;
#pragma unroll
    for (int i = 0; i < 2; i++) {
        int c8 = tid + i * 256;
        int tt = c8 >> 3, d8 = (c8 & 7) * 8;
        size_t rowoff = (size_t)(tok0 + tt) * TD + h * dh;
        bf16x8 k8 = *reinterpret_cast<const bf16x8*>(qkv + rowoff + Dc + d8);
        bf16x8 v8 = *reinterpret_cast<const bf16x8*>(qkv + rowoff + 2 * Dc + d8);
        float gv = og[(size_t)(tok0 + tt) * Hc + h];
        float kf[8], vf[8];
#pragma unroll
        for (int j = 0; j < 8; j++) {
            float kv = bf2f(k8[j]);
            kf[j] = kv > 0.f ? kv + 1.f : expf(kv);
            vf[j] = bf2f(v8[j]) * gv;
        }
        *reinterpret_cast<float4*>(&Ks[tt * 64 + d8])     = *reinterpret_cast<float4*>(&kf[0]);
        *reinterpret_cast<float4*>(&Ks[tt * 64 + d8 + 4]) = *reinterpret_cast<float4*>(&kf[4]);
        *reinterpret_cast<float4*>(&Vs[tt * 64 + d8])     = *reinterpret_cast<float4*>(&vf[0]);
        *reinterpret_cast<float4*>(&Vs[tt * 64 + d8 + 4]) = *reinterpret_cast<float4*>(&vf[4]);
    }
    __syncthreads();
    int e = tid & 63, d0 = (tid >> 6) * 16;
    float u[16] = {};
    for (int tt = 0; tt < 64; tt++) {
        float vv = Vs[tt * 64 + e];
        float4 k4[4];
#pragma unroll
        for (int q = 0; q < 4; q++)
            k4[q] = *reinterpret_cast<const float4*>(&Ks[tt * 64 + d0 + q * 4]);
        const float* kk = reinterpret_cast<const float*>(k4);
#pragma unroll
        for (int j = 0; j < 16; j++)
            u[j] = fmaf(kk[j], vv, u[j]);
    }
    // store U^T: SU[bid][e*64 + d]  (contiguous in d per thread)
    float* Uo = SU + (size_t)bid * 4096 + e * 64 + d0;
#pragma unroll
    for (int q = 0; q < 4; q++)
        *reinterpret_cast<float4*>(Uo + q * 4) =
            make_float4(u[q * 4], u[q * 4 + 1], u[q * 4 + 2], u[q * 4 + 3]);
    if (tid < 64) {
        float zsum = 0.f;
        for (int tt = 0; tt < 64; tt++) zsum += Ks[tt * 64 + tid];
        zc[bid * 64 + tid] = zsum;
    }
}

// ---------------- Phase B: exclusive prefix over chunks (one thread per element) ----------------
__global__ __launch_bounds__(256)
void prefix_kernel(float* __restrict__ SU, float* __restrict__ zc) {
    int gid = blockIdx.x * 256 + threadIdx.x;
    if (gid < BH * 4096) {
        int bh = gid >> 12, i = gid & 4095;
        float* S = SU + (size_t)bh * NC * 4096 + i;
        float r[NC];
#pragma unroll
        for (int cc = 0; cc < NC; cc++) r[cc] = S[cc * 4096];
        float run = 0.f;
#pragma unroll
        for (int cc = 0; cc < NC; cc++) { float tv = r[cc]; S[cc * 4096] = run; run += tv; }
    } else {
        int g2 = gid - BH * 4096;
        if (g2 < BH * 64) {
            int bh = g2 >> 6, i = g2 & 63;
            float* z = zc + (size_t)bh * NC * 64 + i;
            float r[NC];
#pragma unroll
            for (int cc = 0; cc < NC; cc++) r[cc] = z[cc * 64];
            float run = 0.f;
#pragma unroll
            for (int cc = 0; cc < NC; cc++) { float tv = r[cc]; z[cc * 64] = run; run += tv; }
        }
    }
}

// ---------------- Phase C: MFMA per-chunk output + mini-LN, bf16 out ----------------
// P = Qf Kf^T (masked), O = [P | Qf] @ [Vg ; S]  with den folded in as column e=64.
constexpr int LQ = 72;    // padded row stride for 64-col bf16 tiles (36 dwords)
constexpr int LB = 136;   // padded row stride for 128-col bf16 B-tile (68 dwords)
__global__ __launch_bounds__(256)
void phaseC_kernel(const __hip_bfloat16* __restrict__ qkv, const float* __restrict__ og,
                   const float* __restrict__ SU, const float* __restrict__ zc,
                   const float* __restrict__ mn_w, const float* __restrict__ mn_b,
                   __hip_bfloat16* __restrict__ attn) {
    int bid = blockIdx.x;           // bh*16 + c
    int bh = bid >> 4;
    int b = bh / Hc, h = bh % Hc;
    int tok0 = b * Lc + (bid & 15) * CH;
    __shared__ short Qs[64 * LQ];   // q_f  [l][d]
    __shared__ short Ks[64 * LQ];   // k_f  [t][d]
    __shared__ short Ps[64 * LQ];   // masked P [l][t]
    __shared__ short Bst[80 * LB];  // rows e: [V^T*og | S^T]; row64 = [1 | z_start]; 65..79 = 0
    int tid = threadIdx.x;
    int wave = tid >> 6, lane = tid & 63;
    int l16 = lane & 15, l4 = lane >> 4;

    const float* SUp = SU + (size_t)bid * 4096;   // prefixed, [e][d]
    const float* zcp = zc + (size_t)bid * 64;     // prefixed z_start

#pragma unroll
    for (int i = 0; i < 2; i++) {
        int c8 = tid + i * 256;
        int tt = c8 >> 3, d8 = (c8 & 7) * 8;
        size_t rowoff = (size_t)(tok0 + tt) * TD + h * dh;
        bf16x8 q8 = *reinterpret_cast<const bf16x8*>(qkv + rowoff + d8);
        bf16x8 k8 = *reinterpret_cast<const bf16x8*>(qkv + rowoff + Dc + d8);
        bf16x8 v8 = *reinterpret_cast<const bf16x8*>(qkv + rowoff + 2 * Dc + d8);
        float gv = og[(size_t)(tok0 + tt) * Hc + h];
        short qo[8], ko[8];
#pragma unroll
        for (int j = 0; j < 8; j++) {
            float qv = bf2f(q8[j]);
            qo[j] = f2b(qv > 0.f ? qv + 1.f : expf(qv));
            float kv = bf2f(k8[j]);
            ko[j] = f2b(kv > 0.f ? kv + 1.f : expf(kv));
            Bst[(d8 + j) * LB + tt] = f2b(bf2f(v8[j]) * gv);   // V^T transpose write
        }
        *reinterpret_cast<bf16x8*>(&Qs[tt * LQ + d8]) = *reinterpret_cast<bf16x8*>(qo);
        *reinterpret_cast<bf16x8*>(&Ks[tt * LQ + d8]) = *reinterpret_cast<bf16x8*>(ko);
        // S^T part: rows e = tt, cols 64+d8
        float4 sa = *reinterpret_cast<const float4*>(SUp + tt * 64 + d8);
        float4 sb = *reinterpret_cast<const float4*>(SUp + tt * 64 + d8 + 4);
        short so[8] = { f2b(sa.x), f2b(sa.y), f2b(sa.z), f2b(sa.w),
                        f2b(sb.x), f2b(sb.y), f2b(sb.z), f2b(sb.w) };
        *reinterpret_cast<bf16x8*>(&Bst[tt * LB + 64 + d8]) = *reinterpret_cast<bf16x8*>(so);
    }
    if (tid < 64) {
        Bst[64 * LB + tid] = f2b(1.0f);          // ones -> row-sum of P (den part 1)
        Bst[64 * LB + 64 + tid] = f2b(zcp[tid]); // z_start -> q.z (den part 2)
    } else {
        for (int i2 = tid - 64; i2 < 15 * LB; i2 += 192) Bst[65 * LB + i2] = 0;
    }
    __syncthreads();   // barrier 1

    // ---- P = Qf Kf^T : wave owns l-strip [wave*16, wave*16+16) ----
    const short* arow = &Qs[(wave * 16 + l16) * LQ];
    f32x4 accp[4];
#pragma unroll
    for (int j = 0; j < 4; j++) accp[j] = f32x4{0.f, 0.f, 0.f, 0.f};
#pragma unroll
    for (int kk = 0; kk < 2; kk++) {
        bf16x8 af = *reinterpret_cast<const bf16x8*>(&arow[kk * 32 + l4 * 8]);
#pragma unroll
        for (int j = 0; j < 4; j++) {
            bf16x8 bfv = *reinterpret_cast<const bf16x8*>(
                &Ks[(j * 16 + l16) * LQ + kk * 32 + l4 * 8]);
            accp[j] = __builtin_amdgcn_mfma_f32_16x16x32_bf16(af, bfv, accp[j], 0, 0, 0);
        }
    }
    // mask (t<=l) and spill P to LDS bf16
#pragma unroll
    for (int j = 0; j < 4; j++) {
#pragma unroll
        for (int r = 0; r < 4; r++) {
            int l = wave * 16 + l4 * 4 + r;
            int t = j * 16 + l16;
            float pv = (t <= l) ? accp[j][r] : 0.f;
            Ps[l * LQ + t] = f2b(pv);
        }
    }
    __syncthreads();   // barrier 2

    // ---- O = [P | Qf] @ Bst^T : 5 e-tiles (j=4 col 64 = den) ----
    const short* prow = &Ps[(wave * 16 + l16) * LQ];
    f32x4 acc[5];
#pragma unroll
    for (int j = 0; j < 5; j++) acc[j] = f32x4{0.f, 0.f, 0.f, 0.f};
#pragma unroll
    for (int kk = 0; kk < 4; kk++) {
        bf16x8 af = (kk < 2)
            ? *reinterpret_cast<const bf16x8*>(&prow[kk * 32 + l4 * 8])
            : *reinterpret_cast<const bf16x8*>(&arow[(kk - 2) * 32 + l4 * 8]);
#pragma unroll
        for (int j = 0; j < 5; j++) {
            bf16x8 bfv = *reinterpret_cast<const bf16x8*>(
                &Bst[(j * 16 + l16) * LB + kk * 32 + l4 * 8]);
            acc[j] = __builtin_amdgcn_mfma_f32_16x16x32_bf16(af, bfv, acc[j], 0, 0, 0);
        }
    }

    // ---- epilogue: den, mini-LN over e (in-register, shfl over l16 group) ----
#pragma unroll
    for (int r = 0; r < 4; r++) {
        float den = __shfl(acc[4][r], l4 * 16) + 1e-6f;   // col e=64 lives in lane l16==0
        float inv = 1.f / den;
        float v0 = acc[0][r] * inv, v1 = acc[1][r] * inv;
        float v2 = acc[2][r] * inv, v3 = acc[3][r] * inv;
        float s1 = v0 + v1 + v2 + v3;
        float s2 = v0 * v0 + v1 * v1 + v2 * v2 + v3 * v3;
#pragma unroll
        for (int m = 1; m < 16; m <<= 1) {
            s1 += __shfl_xor(s1, m, 64);
            s2 += __shfl_xor(s2, m, 64);
        }
        float mu = s1 * (1.f / 64.f);
        float rstd = rsqrtf(s2 * (1.f / 64.f) - mu * mu + 1e-5f);
        int l = wave * 16 + l4 * 4 + r;
        __hip_bfloat16* orow = attn + (size_t)(tok0 + l) * Dc + h * dh;
        float vj[4] = {v0, v1, v2, v3};
#pragma unroll
        for (int j = 0; j < 4; j++) {
            int e = j * 16 + l16;
            orow[e] = __float2bfloat16((vj[j] - mu) * rstd * mn_w[e] + mn_b[e]);
        }
    }
}

extern "C" void kernel_launch(void* const* d_in, const int* in_sizes, int n_in,
                              void* d_out, int out_size, void* d_ws, size_t ws_size,
                              hipStream_t stream) {
    const float* x     = (const float*)d_in[0];
    const float* Wqkv  = (const float*)d_in[1];
    const float* bqkv  = (const float*)d_in[2];
    const float* Wb1   = (const float*)d_in[3];
    const float* Wb2   = (const float*)d_in[4];
    const float* temp  = (const float*)d_in[5];
    const float* Wproj = (const float*)d_in[6];
    const float* bproj = (const float*)d_in[7];
    const float* ln_w  = (const float*)d_in[8];
    const float* ln_b  = (const float*)d_in[9];
    const float* mn_w  = (const float*)d_in[10];
    const float* mn_b  = (const float*)d_in[11];

    float* out0 = (float*)d_out;                 // [2048, 768]
    float* gate = out0 + (size_t)BL * Dc;        // [2048, 12]

    float* ws   = (float*)d_ws;
    float* tbuf = ws;                            // 2048*128 f32
    float* og   = tbuf + (size_t)BL * Rc;        // 2048*12 f32
    float* SU   = og + (size_t)BL * Hc;          // 24*16*4096 f32 (U^T, [e][d])
    float* zc   = SU + (size_t)BH * NC * 4096;   // 24*16*64 f32
    __hip_bfloat16* bfr = (__hip_bfloat16*)(zc + (size_t)BH * NC * 64);
    __hip_bfloat16* qkvb   = bfr;                        // 2048*2304 bf16
    __hip_bfloat16* xnb    = qkvb + (size_t)BL * TD;     // 2048*768 bf16
    __hip_bfloat16* xb     = xnb + (size_t)BL * Dc;      // 2048*768 bf16 (raw x)
    __hip_bfloat16* attnb  = xb + (size_t)BL * Dc;       // 2048*768 bf16
    __hip_bfloat16* WqkvT  = attnb + (size_t)BL * Dc;    // 2304*768 bf16
    __hip_bfloat16* WprojT = WqkvT + (size_t)TD * Dc;    // 768*768 bf16
    __hip_bfloat16* Wb1T   = WprojT + (size_t)Dc * Dc;   // 128*768 bf16

    // 1. prep: weight transposes + LayerNorm
    prep_kernel<<<NPREP, 256, 0, stream>>>(x, ln_w, ln_b, Wqkv, Wproj, Wb1,
                                           xnb, xb, WqkvT, WprojT, Wb1T);
    // 2. qkv = x_norm @ Wqkv + bqkv   (bf16 MFMA, bf16 out)
    gemm_mfma_kernel<true, 0><<<dim3(TD / 128, BL / 128), 512, 0, stream>>>(
        xnb, WqkvT, bqkv, qkvb, BL, TD, Dc);
    // 3. t = silu(x @ Wb1)   (raw x, bf16 MFMA, fp32 out)
    gemm_mfma_kernel<false, 1><<<dim3(Rc / 128, BL / 128), 512, 0, stream>>>(
        xb, Wb1T, nullptr, tbuf, BL, Rc, Dc);
    // 4. gate + (1+gate)
    gate_kernel<<<BL * Hc / 256, 256, 0, stream>>>(tbuf, Wb2, temp, gate, og);
    // 5. per-chunk local KV state sums (raw, [e][d])
    phaseA_kernel<<<BH * NC, 256, 0, stream>>>(qkvb, og, SU, zc);
    // 6. exclusive prefix over chunks
    prefix_kernel<<<(BH * 4096 + BH * 64 + 255) / 256, 256, 0, stream>>>(SU, zc);
    // 7. per-chunk outputs (MFMA) + mini-LN -> bf16
    phaseC_kernel<<<BH * NC, 256, 0, stream>>>(qkvb, og, SU, zc, mn_w, mn_b, attnb);
    // 8. out0 = attn @ Wproj + bproj  (bf16 MFMA, fp32 out)
    gemm_mfma_kernel<false, 0><<<dim3(Dc / 128, BL / 128), 512, 0, stream>>>(
        attnb, WprojT, bproj, out0, BL, Dc, Dc);
}

// Round 7
// 69.940 us; speedup vs baseline: 2.1902x; 1.1929x over previous
//
#include <hip/hip_runtime.h>
#include <hip/hip_bf16.h>
#include <math.h>

// Problem constants
constexpr int Bc = 2, Lc = 1024, Dc = 768, Hc = 12, dh = 64, Rc = 128;
constexpr int BL = Bc * Lc;          // 2048 tokens
constexpr int TD = 3 * Dc;           // 2304
constexpr int CH = 64;               // chunk length
constexpr int NC = Lc / CH;          // 16 chunks per sequence
constexpr int BH = Bc * Hc;          // 24

typedef __attribute__((ext_vector_type(8))) short bf16x8;
typedef __attribute__((ext_vector_type(4))) float f32x4;

__device__ __forceinline__ float bf2f(short u) {
    union { float f; unsigned int i; } c;
    c.i = ((unsigned int)(unsigned short)u) << 16;
    return c.f;
}
__device__ __forceinline__ short f2b(float f) {
    __hip_bfloat16 h = __float2bfloat16(f);
    return *reinterpret_cast<short*>(&h);
}

#define GLOAD_LDS16(gp, lp)                                                        \
    __builtin_amdgcn_global_load_lds(                                              \
        (const __attribute__((address_space(1))) void*)(gp),                       \
        (__attribute__((address_space(3))) void*)(lp), 16, 0, 0)

// ---------------- Prep: 3 weight transposes + LayerNorm, one kernel ----------------
__device__ __forceinline__ void do_transpose(const float* __restrict__ W,
                                             __hip_bfloat16* __restrict__ WT,
                                             int K, int N, int bx, int by,
                                             int tid, float* t) {
    int k0 = by * 32, n0 = bx * 32;
    int r = tid >> 5, c = tid & 31;   // r in 0..7
#pragma unroll
    for (int i = 0; i < 4; i++)
        t[(r + i * 8) * 33 + c] = W[(size_t)(k0 + r + i * 8) * N + n0 + c];
    __syncthreads();
#pragma unroll
    for (int i = 0; i < 4; i++)
        WT[(size_t)(n0 + r + i * 8) * K + k0 + c] = __float2bfloat16(t[c * 33 + r + i * 8]);
}

constexpr int NT1 = (TD / 32) * (Dc / 32);   // 1728  Wqkv
constexpr int NT2 = (Dc / 32) * (Dc / 32);   // 576   Wproj
constexpr int NT3 = (Rc / 32) * (Dc / 32);   // 96    Wb1
constexpr int NPREP = NT1 + NT2 + NT3 + BL;  // + 2048 LN rows

__global__ __launch_bounds__(256)
void prep_kernel(const float* __restrict__ x, const float* __restrict__ ln_w,
                 const float* __restrict__ ln_b,
                 const float* __restrict__ Wqkv, const float* __restrict__ Wproj,
                 const float* __restrict__ Wb1,
                 __hip_bfloat16* __restrict__ xnb, __hip_bfloat16* __restrict__ xb,
                 __hip_bfloat16* __restrict__ WqkvT, __hip_bfloat16* __restrict__ WprojT,
                 __hip_bfloat16* __restrict__ Wb1T) {
    __shared__ float shm[32 * 33];
    int bid = blockIdx.x, tid = threadIdx.x;
    if (bid < NT1) { do_transpose(Wqkv, WqkvT, Dc, TD, bid % 72, bid / 72, tid, shm); return; }
    bid -= NT1;
    if (bid < NT2) { do_transpose(Wproj, WprojT, Dc, Dc, bid % 24, bid / 24, tid, shm); return; }
    bid -= NT2;
    if (bid < NT3) { do_transpose(Wb1, Wb1T, Dc, Rc, bid % 4, bid / 4, tid, shm); return; }
    bid -= NT3;
    // LayerNorm row
    int row = bid;
    const float* xr = x + (size_t)row * Dc;
    __hip_bfloat16* yr = xnb + (size_t)row * Dc;
    __hip_bfloat16* xbr = xb + (size_t)row * Dc;
    float v[3];
    float s = 0.f;
#pragma unroll
    for (int i = 0; i < 3; i++) { v[i] = xr[tid + i * 256]; s += v[i]; }
    shm[tid] = s; __syncthreads();
    for (int off = 128; off > 0; off >>= 1) {
        if (tid < off) shm[tid] += shm[tid + off];
        __syncthreads();
    }
    float mu = shm[0] / (float)Dc;
    __syncthreads();
    float s2 = 0.f;
#pragma unroll
    for (int i = 0; i < 3; i++) { float d = v[i] - mu; s2 += d * d; }
    shm[tid] = s2; __syncthreads();
    for (int off = 128; off > 0; off >>= 1) {
        if (tid < off) shm[tid] += shm[tid + off];
        __syncthreads();
    }
    float rstd = rsqrtf(shm[0] / (float)Dc + 1e-5f);
#pragma unroll
    for (int i = 0; i < 3; i++) {
        int c = tid + i * 256;
        yr[c] = __float2bfloat16((v[i] - mu) * rstd * ln_w[c] + ln_b[c]);
        xbr[c] = __float2bfloat16(v[i]);
    }
}

// ---------------- Fat GEMM dispatch: qkv (288 blocks) + bottleneck silu (16 blocks) ----------------
// Same staging/compute as gemm_mfma_kernel; per-block runtime config; XCD swizzle.
constexpr int NQB = (TD / 128) * (BL / 128);   // 288
constexpr int NFAT = NQB + BL / 128;           // 304
__global__ __launch_bounds__(512)
void fat_gemm_kernel(const __hip_bfloat16* __restrict__ A1,
                     const __hip_bfloat16* __restrict__ B1,
                     const float* __restrict__ bias1,
                     __hip_bfloat16* __restrict__ C1,
                     const __hip_bfloat16* __restrict__ A2,
                     const __hip_bfloat16* __restrict__ B2,
                     float* __restrict__ C2) {
    __shared__ short lds[2][2][128 * 64];
    int bid = blockIdx.x;
    bid = (bid & 7) * (NFAT / 8) + (bid >> 3);          // bijective: 304 % 8 == 0
    bool isq = bid < NQB;
    int bx, by, N;
    const __hip_bfloat16 *A, *BT;
    if (isq) { bx = bid % 18; by = bid / 18; A = A1; BT = B1; N = TD; }
    else     { int b2 = bid - NQB; bx = 0; by = b2; A = A2; BT = B2; N = Rc; }
    const int K = Dc;

    int tid = threadIdx.x;
    int wave = tid >> 6, lane = tid & 63;
    int l16 = lane & 15, l4 = lane >> 4;
    int m0 = by * 128, n0 = bx * 128;

    int ab = wave >> 2;
    int r_in = lane >> 3;
    int s_src = (lane & 7) ^ r_in;
    const __hip_bfloat16* gbase = ab ? (BT + (size_t)n0 * K) : (A + (size_t)m0 * K);
    const __hip_bfloat16* gsrc =
        gbase + (size_t)((wave & 3) * 32 + r_in) * K + s_src * 8;

    int wr = (wave >> 2) * 64, wc = (wave & 3) * 32;
    int xs = l16 & 7;

    f32x4 acc[4][2];
#pragma unroll
    for (int i = 0; i < 4; i++)
#pragma unroll
        for (int j = 0; j < 2; j++) acc[i][j] = f32x4{0.f, 0.f, 0.f, 0.f};

    auto stage = [&](int buf, int kt) {
        const __hip_bfloat16* g = gsrc + kt * 64;
        short* lb = &lds[buf][ab][(wave & 3) * 32 * 64];
#pragma unroll
        for (int i = 0; i < 4; i++)
            GLOAD_LDS16(g + (size_t)i * 8 * K, lb + i * 8 * 64);
    };
    auto compute = [&](int buf) {
        const short* As = &lds[buf][0][0];
        const short* Bs = &lds[buf][1][0];
#pragma unroll
        for (int kk = 0; kk < 2; kk++) {
            bf16x8 af[4], bfr[2];
            int slot = (kk * 4 + l4) ^ xs;
#pragma unroll
            for (int f = 0; f < 4; f++)
                af[f] = *reinterpret_cast<const bf16x8*>(
                    &As[(wr + f * 16 + l16) * 64 + slot * 8]);
#pragma unroll
            for (int f = 0; f < 2; f++)
                bfr[f] = *reinterpret_cast<const bf16x8*>(
                    &Bs[(wc + f * 16 + l16) * 64 + slot * 8]);
#pragma unroll
            for (int i = 0; i < 4; i++)
#pragma unroll
                for (int j = 0; j < 2; j++)
                    acc[i][j] = __builtin_amdgcn_mfma_f32_16x16x32_bf16(
                        af[i], bfr[j], acc[i][j], 0, 0, 0);
        }
    };

    int NT = K / 64;
    int cur = 0;
    stage(0, 0);
    __syncthreads();
    for (int t = 0; t < NT; t++) {
        if (t + 1 < NT) stage(cur ^ 1, t + 1);
        compute(cur);
        if (t + 1 < NT) { __syncthreads(); cur ^= 1; }
    }

    int crow = l4 * 4;
#pragma unroll
    for (int i = 0; i < 4; i++) {
#pragma unroll
        for (int j = 0; j < 2; j++) {
            int col = n0 + wc + j * 16 + l16;
            float bb = isq ? bias1[col] : 0.f;
#pragma unroll
            for (int r = 0; r < 4; r++) {
                int rowm = m0 + wr + i * 16 + crow + r;
                float v = acc[i][j][r] + bb;
                if (isq) {
                    C1[(size_t)rowm * N + col] = __float2bfloat16(v);
                } else {
                    v = v / (1.f + expf(-v));            // silu
                    C2[(size_t)rowm * N + col] = v;
                }
            }
        }
    }
}

// ---------------- bf16 MFMA GEMM (proj), 1D grid + XCD swizzle ----------------
template <bool OUT_BF16, int ACT>
__global__ __launch_bounds__(512)
void gemm_mfma_kernel(const __hip_bfloat16* __restrict__ A,
                      const __hip_bfloat16* __restrict__ BT,
                      const float* __restrict__ bias,
                      void* __restrict__ Cout, int M, int N, int K, int nbx) {
    __shared__ short lds[2][2][128 * 64];
    int nwg = gridDim.x;
    int bid = blockIdx.x;
    if ((nwg & 7) == 0) bid = (bid & 7) * (nwg >> 3) + (bid >> 3);
    int m0 = (bid / nbx) * 128, n0 = (bid % nbx) * 128;

    int tid = threadIdx.x;
    int wave = tid >> 6, lane = tid & 63;
    int l16 = lane & 15, l4 = lane >> 4;

    int ab = wave >> 2;
    int r_in = lane >> 3;
    int s_src = (lane & 7) ^ r_in;
    const __hip_bfloat16* gbase = ab ? (BT + (size_t)n0 * K) : (A + (size_t)m0 * K);
    const __hip_bfloat16* gsrc =
        gbase + (size_t)((wave & 3) * 32 + r_in) * K + s_src * 8;

    int wr = (wave >> 2) * 64, wc = (wave & 3) * 32;
    int xs = l16 & 7;

    f32x4 acc[4][2];
#pragma unroll
    for (int i = 0; i < 4; i++)
#pragma unroll
        for (int j = 0; j < 2; j++) acc[i][j] = f32x4{0.f, 0.f, 0.f, 0.f};

    auto stage = [&](int buf, int kt) {
        const __hip_bfloat16* g = gsrc + kt * 64;
        short* lb = &lds[buf][ab][(wave & 3) * 32 * 64];
#pragma unroll
        for (int i = 0; i < 4; i++)
            GLOAD_LDS16(g + (size_t)i * 8 * K, lb + i * 8 * 64);
    };
    auto compute = [&](int buf) {
        const short* As = &lds[buf][0][0];
        const short* Bs = &lds[buf][1][0];
#pragma unroll
        for (int kk = 0; kk < 2; kk++) {
            bf16x8 af[4], bfr[2];
            int slot = (kk * 4 + l4) ^ xs;
#pragma unroll
            for (int f = 0; f < 4; f++)
                af[f] = *reinterpret_cast<const bf16x8*>(
                    &As[(wr + f * 16 + l16) * 64 + slot * 8]);
#pragma unroll
            for (int f = 0; f < 2; f++)
                bfr[f] = *reinterpret_cast<const bf16x8*>(
                    &Bs[(wc + f * 16 + l16) * 64 + slot * 8]);
#pragma unroll
            for (int i = 0; i < 4; i++)
#pragma unroll
                for (int j = 0; j < 2; j++)
                    acc[i][j] = __builtin_amdgcn_mfma_f32_16x16x32_bf16(
                        af[i], bfr[j], acc[i][j], 0, 0, 0);
        }
    };

    int NT = K / 64;
    int cur = 0;
    stage(0, 0);
    __syncthreads();
    for (int t = 0; t < NT; t++) {
        if (t + 1 < NT) stage(cur ^ 1, t + 1);
        compute(cur);
        if (t + 1 < NT) { __syncthreads(); cur ^= 1; }
    }

    int crow = l4 * 4;
#pragma unroll
    for (int i = 0; i < 4; i++) {
#pragma unroll
        for (int j = 0; j < 2; j++) {
            int col = n0 + wc + j * 16 + l16;
            float bb = bias ? bias[col] : 0.f;
#pragma unroll
            for (int r = 0; r < 4; r++) {
                int rowm = m0 + wr + i * 16 + crow + r;
                float v = acc[i][j][r] + bb;
                if (ACT == 1) v = v / (1.f + expf(-v));
                if (OUT_BF16)
                    ((__hip_bfloat16*)Cout)[(size_t)rowm * N + col] = __float2bfloat16(v);
                else
                    ((float*)Cout)[(size_t)rowm * N + col] = v;
            }
        }
    }
}

// ---------------- Phase A (+fused gate): U_c^T ([e][d]), zc, gate ----------------
__global__ __launch_bounds__(256)
void phaseA_kernel(const __hip_bfloat16* __restrict__ qkv, const float* __restrict__ tbuf,
                   const float* __restrict__ Wb2, const float* __restrict__ temperature,
                   float* __restrict__ gate_out,
                   float* __restrict__ SU, float* __restrict__ zc) {
    int bid = blockIdx.x;           // bh*16 + c
    int bh = bid >> 4, c = bid & 15;
    int b = bh / Hc, h = bh % Hc;
    int tok0 = b * Lc + c * CH;
    __shared__ float Ks[64 * 64];
    __shared__ float Vs[64 * 64];   // raw v (og folded at compute)
    __shared__ float ogs[64];
    int tid = threadIdx.x;
#pragma unroll
    for (int i = 0; i < 2; i++) {
        int c8 = tid + i * 256;
        int tt = c8 >> 3, d8 = (c8 & 7) * 8;
        size_t rowoff = (size_t)(tok0 + tt) * TD + h * dh;
        bf16x8 k8 = *reinterpret_cast<const bf16x8*>(qkv + rowoff + Dc + d8);
        bf16x8 v8 = *reinterpret_cast<const bf16x8*>(qkv + rowoff + 2 * Dc + d8);
        float kf[8], vf[8];
#pragma unroll
        for (int j = 0; j < 8; j++) {
            float kv = bf2f(k8[j]);
            kf[j] = kv > 0.f ? kv + 1.f : expf(kv);
            vf[j] = bf2f(v8[j]);
        }
        *reinterpret_cast<float4*>(&Ks[tt * 64 + d8])     = *reinterpret_cast<float4*>(&kf[0]);
        *reinterpret_cast<float4*>(&Ks[tt * 64 + d8 + 4]) = *reinterpret_cast<float4*>(&kf[4]);
        *reinterpret_cast<float4*>(&Vs[tt * 64 + d8])     = *reinterpret_cast<float4*>(&vf[0]);
        *reinterpret_cast<float4*>(&Vs[tt * 64 + d8 + 4]) = *reinterpret_cast<float4*>(&vf[4]);
    }
    // gate for this block's 64 tokens (head h), one thread per token
    if (tid < 64) {
        const float* tr = tbuf + (size_t)(tok0 + tid) * Rc;
        float p0 = 0.f, p1 = 0.f, p2 = 0.f, p3 = 0.f, p4 = 0.f;
#pragma unroll 4
        for (int r = 0; r < Rc; r++) {
            float tv = tr[r];
            const float* wr = Wb2 + r * (Hc * 5) + h * 5;
            p0 = fmaf(tv, wr[0], p0);
            p1 = fmaf(tv, wr[1], p1);
            p2 = fmaf(tv, wr[2], p2);
            p3 = fmaf(tv, wr[3], p3);
            p4 = fmaf(tv, wr[4], p4);
        }
        const float PI = 3.14159265358979323846f;
        float sem_amp = 1.f / (1.f + expf(-p0));
        float sem_phase = tanhf(p1) * PI;
        float ctx_amp = 1.f / (1.f + expf(-p2));
        float ctx_phase = tanhf(p3) * PI;
        float temp = fminf(fmaxf(temperature[0], 0.1f), 2.0f);
        float inter = tanhf(sem_amp * ctx_amp * cosf(sem_phase - ctx_phase)) * temp;
        float g = 1.f / (1.f + expf(-inter));
        gate_out[(size_t)(tok0 + tid) * Hc + h] = g;
        ogs[tid] = 1.f + g;
    }
    __syncthreads();
    int e = tid & 63, d0 = (tid >> 6) * 16;
    float u[16] = {};
    for (int tt = 0; tt < 64; tt++) {
        float vv = Vs[tt * 64 + e] * ogs[tt];
        float4 k4[4];
#pragma unroll
        for (int q = 0; q < 4; q++)
            k4[q] = *reinterpret_cast<const float4*>(&Ks[tt * 64 + d0 + q * 4]);
        const float* kk = reinterpret_cast<const float*>(k4);
#pragma unroll
        for (int j = 0; j < 16; j++)
            u[j] = fmaf(kk[j], vv, u[j]);
    }
    float* Uo = SU + (size_t)bid * 4096 + e * 64 + d0;
#pragma unroll
    for (int q = 0; q < 4; q++)
        *reinterpret_cast<float4*>(Uo + q * 4) =
            make_float4(u[q * 4], u[q * 4 + 1], u[q * 4 + 2], u[q * 4 + 3]);
    if (tid < 64) {
        float zsum = 0.f;
        for (int tt = 0; tt < 64; tt++) zsum += Ks[tt * 64 + tid];
        zc[bid * 64 + tid] = zsum;
    }
}

// ---------------- Phase B: exclusive prefix over chunks (one thread per element) ----------------
__global__ __launch_bounds__(256)
void prefix_kernel(float* __restrict__ SU, float* __restrict__ zc) {
    int gid = blockIdx.x * 256 + threadIdx.x;
    if (gid < BH * 4096) {
        int bh = gid >> 12, i = gid & 4095;
        float* S = SU + (size_t)bh * NC * 4096 + i;
        float r[NC];
#pragma unroll
        for (int cc = 0; cc < NC; cc++) r[cc] = S[cc * 4096];
        float run = 0.f;
#pragma unroll
        for (int cc = 0; cc < NC; cc++) { float tv = r[cc]; S[cc * 4096] = run; run += tv; }
    } else {
        int g2 = gid - BH * 4096;
        if (g2 < BH * 64) {
            int bh = g2 >> 6, i = g2 & 63;
            float* z = zc + (size_t)bh * NC * 64 + i;
            float r[NC];
#pragma unroll
            for (int cc = 0; cc < NC; cc++) r[cc] = z[cc * 64];
            float run = 0.f;
#pragma unroll
            for (int cc = 0; cc < NC; cc++) { float tv = r[cc]; z[cc * 64] = run; run += tv; }
        }
    }
}

// ---------------- Phase C: MFMA per-chunk output + mini-LN, bf16 out ----------------
constexpr int LQ = 72;    // padded row stride for 64-col bf16 tiles (36 dwords)
constexpr int LB = 136;   // padded row stride for 128-col bf16 B-tile (68 dwords)
__global__ __launch_bounds__(256)
void phaseC_kernel(const __hip_bfloat16* __restrict__ qkv, const float* __restrict__ gate,
                   const float* __restrict__ SU, const float* __restrict__ zc,
                   const float* __restrict__ mn_w, const float* __restrict__ mn_b,
                   __hip_bfloat16* __restrict__ attn) {
    int bid = blockIdx.x;           // bh*16 + c
    int bh = bid >> 4;
    int b = bh / Hc, h = bh % Hc;
    int tok0 = b * Lc + (bid & 15) * CH;
    __shared__ short Qs[64 * LQ];   // q_f  [l][d]
    __shared__ short Ks[64 * LQ];   // k_f  [t][d]
    __shared__ short Ps[64 * LQ];   // masked P [l][t]
    __shared__ short Bst[80 * LB];  // rows e: [V^T*og | S^T]; row64 = [1 | z_start]; 65..79 = 0
    int tid = threadIdx.x;
    int wave = tid >> 6, lane = tid & 63;
    int l16 = lane & 15, l4 = lane >> 4;

    const float* SUp = SU + (size_t)bid * 4096;   // prefixed, [e][d]
    const float* zcp = zc + (size_t)bid * 64;     // prefixed z_start

#pragma unroll
    for (int i = 0; i < 2; i++) {
        int c8 = tid + i * 256;
        int tt = c8 >> 3, d8 = (c8 & 7) * 8;
        size_t rowoff = (size_t)(tok0 + tt) * TD + h * dh;
        bf16x8 q8 = *reinterpret_cast<const bf16x8*>(qkv + rowoff + d8);
        bf16x8 k8 = *reinterpret_cast<const bf16x8*>(qkv + rowoff + Dc + d8);
        bf16x8 v8 = *reinterpret_cast<const bf16x8*>(qkv + rowoff + 2 * Dc + d8);
        float gv = 1.f + gate[(size_t)(tok0 + tt) * Hc + h];
        short qo[8], ko[8];
#pragma unroll
        for (int j = 0; j < 8; j++) {
            float qv = bf2f(q8[j]);
            qo[j] = f2b(qv > 0.f ? qv + 1.f : expf(qv));
            float kv = bf2f(k8[j]);
            ko[j] = f2b(kv > 0.f ? kv + 1.f : expf(kv));
            Bst[(d8 + j) * LB + tt] = f2b(bf2f(v8[j]) * gv);   // V^T transpose write
        }
        *reinterpret_cast<bf16x8*>(&Qs[tt * LQ + d8]) = *reinterpret_cast<bf16x8*>(qo);
        *reinterpret_cast<bf16x8*>(&Ks[tt * LQ + d8]) = *reinterpret_cast<bf16x8*>(ko);
        float4 sa = *reinterpret_cast<const float4*>(SUp + tt * 64 + d8);
        float4 sb = *reinterpret_cast<const float4*>(SUp + tt * 64 + d8 + 4);
        short so[8] = { f2b(sa.x), f2b(sa.y), f2b(sa.z), f2b(sa.w),
                        f2b(sb.x), f2b(sb.y), f2b(sb.z), f2b(sb.w) };
        *reinterpret_cast<bf16x8*>(&Bst[tt * LB + 64 + d8]) = *reinterpret_cast<bf16x8*>(so);
    }
    if (tid < 64) {
        Bst[64 * LB + tid] = f2b(1.0f);          // ones -> row-sum of P (den part 1)
        Bst[64 * LB + 64 + tid] = f2b(zcp[tid]); // z_start -> q.z (den part 2)
    } else {
        for (int i2 = tid - 64; i2 < 15 * LB; i2 += 192) Bst[65 * LB + i2] = 0;
    }
    __syncthreads();   // barrier 1

    // ---- P = Qf Kf^T : wave owns l-strip [wave*16, wave*16+16) ----
    const short* arow = &Qs[(wave * 16 + l16) * LQ];
    f32x4 accp[4];
#pragma unroll
    for (int j = 0; j < 4; j++) accp[j] = f32x4{0.f, 0.f, 0.f, 0.f};
#pragma unroll
    for (int kk = 0; kk < 2; kk++) {
        bf16x8 af = *reinterpret_cast<const bf16x8*>(&arow[kk * 32 + l4 * 8]);
#pragma unroll
        for (int j = 0; j < 4; j++) {
            bf16x8 bfv = *reinterpret_cast<const bf16x8*>(
                &Ks[(j * 16 + l16) * LQ + kk * 32 + l4 * 8]);
            accp[j] = __builtin_amdgcn_mfma_f32_16x16x32_bf16(af, bfv, accp[j], 0, 0, 0);
        }
    }
#pragma unroll
    for (int j = 0; j < 4; j++) {
#pragma unroll
        for (int r = 0; r < 4; r++) {
            int l = wave * 16 + l4 * 4 + r;
            int t = j * 16 + l16;
            float pv = (t <= l) ? accp[j][r] : 0.f;
            Ps[l * LQ + t] = f2b(pv);
        }
    }
    __syncthreads();   // barrier 2

    // ---- O = [P | Qf] @ Bst^T : 5 e-tiles (j=4 col 64 = den) ----
    const short* prow = &Ps[(wave * 16 + l16) * LQ];
    f32x4 acc[5];
#pragma unroll
    for (int j = 0; j < 5; j++) acc[j] = f32x4{0.f, 0.f, 0.f, 0.f};
#pragma unroll
    for (int kk = 0; kk < 4; kk++) {
        bf16x8 af = (kk < 2)
            ? *reinterpret_cast<const bf16x8*>(&prow[kk * 32 + l4 * 8])
            : *reinterpret_cast<const bf16x8*>(&arow[(kk - 2) * 32 + l4 * 8]);
#pragma unroll
        for (int j = 0; j < 5; j++) {
            bf16x8 bfv = *reinterpret_cast<const bf16x8*>(
                &Bst[(j * 16 + l16) * LB + kk * 32 + l4 * 8]);
            acc[j] = __builtin_amdgcn_mfma_f32_16x16x32_bf16(af, bfv, acc[j], 0, 0, 0);
        }
    }

    // ---- epilogue: den, mini-LN over e (in-register, shfl over l16 group) ----
#pragma unroll
    for (int r = 0; r < 4; r++) {
        float den = __shfl(acc[4][r], l4 * 16) + 1e-6f;
        float inv = 1.f / den;
        float v0 = acc[0][r] * inv, v1 = acc[1][r] * inv;
        float v2 = acc[2][r] * inv, v3 = acc[3][r] * inv;
        float s1 = v0 + v1 + v2 + v3;
        float s2 = v0 * v0 + v1 * v1 + v2 * v2 + v3 * v3;
#pragma unroll
        for (int m = 1; m < 16; m <<= 1) {
            s1 += __shfl_xor(s1, m, 64);
            s2 += __shfl_xor(s2, m, 64);
        }
        float mu = s1 * (1.f / 64.f);
        float rstd = rsqrtf(s2 * (1.f / 64.f) - mu * mu + 1e-5f);
        int l = wave * 16 + l4 * 4 + r;
        __hip_bfloat16* orow = attn + (size_t)(tok0 + l) * Dc + h * dh;
        float vj[4] = {v0, v1, v2, v3};
#pragma unroll
        for (int j = 0; j < 4; j++) {
            int e = j * 16 + l16;
            orow[e] = __float2bfloat16((vj[j] - mu) * rstd * mn_w[e] + mn_b[e]);
        }
    }
}

extern "C" void kernel_launch(void* const* d_in, const int* in_sizes, int n_in,
                              void* d_out, int out_size, void* d_ws, size_t ws_size,
                              hipStream_t stream) {
    const float* x     = (const float*)d_in[0];
    const float* Wqkv  = (const float*)d_in[1];
    const float* bqkv  = (const float*)d_in[2];
    const float* Wb1   = (const float*)d_in[3];
    const float* Wb2   = (const float*)d_in[4];
    const float* temp  = (const float*)d_in[5];
    const float* Wproj = (const float*)d_in[6];
    const float* bproj = (const float*)d_in[7];
    const float* ln_w  = (const float*)d_in[8];
    const float* ln_b  = (const float*)d_in[9];
    const float* mn_w  = (const float*)d_in[10];
    const float* mn_b  = (const float*)d_in[11];

    float* out0 = (float*)d_out;                 // [2048, 768]
    float* gate = out0 + (size_t)BL * Dc;        // [2048, 12]

    float* ws   = (float*)d_ws;
    float* tbuf = ws;                            // 2048*128 f32
    float* SU   = tbuf + (size_t)BL * Rc;        // 24*16*4096 f32 (U^T, [e][d])
    float* zc   = SU + (size_t)BH * NC * 4096;   // 24*16*64 f32
    __hip_bfloat16* bfr = (__hip_bfloat16*)(zc + (size_t)BH * NC * 64);
    __hip_bfloat16* qkvb   = bfr;                        // 2048*2304 bf16
    __hip_bfloat16* xnb    = qkvb + (size_t)BL * TD;     // 2048*768 bf16
    __hip_bfloat16* xb     = xnb + (size_t)BL * Dc;      // 2048*768 bf16 (raw x)
    __hip_bfloat16* attnb  = xb + (size_t)BL * Dc;       // 2048*768 bf16
    __hip_bfloat16* WqkvT  = attnb + (size_t)BL * Dc;    // 2304*768 bf16
    __hip_bfloat16* WprojT = WqkvT + (size_t)TD * Dc;    // 768*768 bf16
    __hip_bfloat16* Wb1T   = WprojT + (size_t)Dc * Dc;   // 128*768 bf16

    // 1. prep: weight transposes + LayerNorm
    prep_kernel<<<NPREP, 256, 0, stream>>>(x, ln_w, ln_b, Wqkv, Wproj, Wb1,
                                           xnb, xb, WqkvT, WprojT, Wb1T);
    // 2. fat dispatch: qkv GEMM (bf16 out) + bottleneck silu GEMM (fp32 out)
    fat_gemm_kernel<<<NFAT, 512, 0, stream>>>(xnb, WqkvT, bqkv, qkvb, xb, Wb1T, tbuf);
    // 3. phaseA: per-chunk U^T + z sums + fused gate (writes gate output)
    phaseA_kernel<<<BH * NC, 256, 0, stream>>>(qkvb, tbuf, Wb2, temp, gate, SU, zc);
    // 4. exclusive prefix over chunks
    prefix_kernel<<<(BH * 4096 + BH * 64 + 255) / 256, 256, 0, stream>>>(SU, zc);
    // 5. per-chunk outputs (MFMA) + mini-LN -> bf16
    phaseC_kernel<<<BH * NC, 256, 0, stream>>>(qkvb, gate, SU, zc, mn_w, mn_b, attnb);
    // 6. out0 = attn @ Wproj + bproj  (bf16 MFMA, fp32 out)
    gemm_mfma_kernel<false, 0><<<(Dc / 128) * (BL / 128), 512, 0, stream>>>(
        attnb, WprojT, bproj, out0, BL, Dc, Dc, Dc / 128);
}

// Round 8
// 58.273 us; speedup vs baseline: 2.6287x; 1.2002x over previous
//
#include <hip/hip_runtime.h>
#include <hip/hip_bf16.h>
#include <math.h>

// Problem constants
constexpr int Bc = 2, Lc = 1024, Dc = 768, Hc = 12, dh = 64, Rc = 128;
constexpr int BL = Bc * Lc;          // 2048 tokens
constexpr int TD = 3 * Dc;           // 2304
constexpr int CH = 64;               // chunk length
constexpr int NC = Lc / CH;          // 16 chunks per sequence
constexpr int BH = Bc * Hc;          // 24

typedef __attribute__((ext_vector_type(8))) short bf16x8;
typedef __attribute__((ext_vector_type(4))) float f32x4;

__device__ __forceinline__ float bf2f(short u) {
    union { float f; unsigned int i; } c;
    c.i = ((unsigned int)(unsigned short)u) << 16;
    return c.f;
}
__device__ __forceinline__ short f2b(float f) {
    __hip_bfloat16 h = __float2bfloat16(f);
    return *reinterpret_cast<short*>(&h);
}

#define GLOAD_LDS16(gp, lp)                                                        \
    __builtin_amdgcn_global_load_lds(                                              \
        (const __attribute__((address_space(1))) void*)(gp),                       \
        (__attribute__((address_space(3))) void*)(lp), 16, 0, 0)

// ---------------- Prep: 3 weight transposes + LayerNorm, one kernel ----------------
__device__ __forceinline__ void do_transpose(const float* __restrict__ W,
                                             __hip_bfloat16* __restrict__ WT,
                                             int K, int N, int bx, int by,
                                             int tid, float* t) {
    int k0 = by * 32, n0 = bx * 32;
    int r = tid >> 5, c = tid & 31;   // r in 0..7
#pragma unroll
    for (int i = 0; i < 4; i++)
        t[(r + i * 8) * 33 + c] = W[(size_t)(k0 + r + i * 8) * N + n0 + c];
    __syncthreads();
#pragma unroll
    for (int i = 0; i < 4; i++)
        WT[(size_t)(n0 + r + i * 8) * K + k0 + c] = __float2bfloat16(t[c * 33 + r + i * 8]);
}

constexpr int NT1 = (TD / 32) * (Dc / 32);   // 1728  Wqkv
constexpr int NT2 = (Dc / 32) * (Dc / 32);   // 576   Wproj
constexpr int NT3 = (Rc / 32) * (Dc / 32);   // 96    Wb1
constexpr int NPREP = NT1 + NT2 + NT3 + BL;  // + 2048 LN rows

__global__ __launch_bounds__(256)
void prep_kernel(const float* __restrict__ x, const float* __restrict__ ln_w,
                 const float* __restrict__ ln_b,
                 const float* __restrict__ Wqkv, const float* __restrict__ Wproj,
                 const float* __restrict__ Wb1,
                 __hip_bfloat16* __restrict__ xnb, __hip_bfloat16* __restrict__ xb,
                 __hip_bfloat16* __restrict__ WqkvT, __hip_bfloat16* __restrict__ WprojT,
                 __hip_bfloat16* __restrict__ Wb1T) {
    __shared__ float shm[32 * 33];
    int bid = blockIdx.x, tid = threadIdx.x;
    if (bid < NT1) { do_transpose(Wqkv, WqkvT, Dc, TD, bid % 72, bid / 72, tid, shm); return; }
    bid -= NT1;
    if (bid < NT2) { do_transpose(Wproj, WprojT, Dc, Dc, bid % 24, bid / 24, tid, shm); return; }
    bid -= NT2;
    if (bid < NT3) { do_transpose(Wb1, Wb1T, Dc, Rc, bid % 4, bid / 4, tid, shm); return; }
    bid -= NT3;
    // LayerNorm row
    int row = bid;
    const float* xr = x + (size_t)row * Dc;
    __hip_bfloat16* yr = xnb + (size_t)row * Dc;
    __hip_bfloat16* xbr = xb + (size_t)row * Dc;
    float v[3];
    float s = 0.f;
#pragma unroll
    for (int i = 0; i < 3; i++) { v[i] = xr[tid + i * 256]; s += v[i]; }
    shm[tid] = s; __syncthreads();
    for (int off = 128; off > 0; off >>= 1) {
        if (tid < off) shm[tid] += shm[tid + off];
        __syncthreads();
    }
    float mu = shm[0] / (float)Dc;
    __syncthreads();
    float s2 = 0.f;
#pragma unroll
    for (int i = 0; i < 3; i++) { float d = v[i] - mu; s2 += d * d; }
    shm[tid] = s2; __syncthreads();
    for (int off = 128; off > 0; off >>= 1) {
        if (tid < off) shm[tid] += shm[tid + off];
        __syncthreads();
    }
    float rstd = rsqrtf(shm[0] / (float)Dc + 1e-5f);
#pragma unroll
    for (int i = 0; i < 3; i++) {
        int c = tid + i * 256;
        yr[c] = __float2bfloat16((v[i] - mu) * rstd * ln_w[c] + ln_b[c]);
        xbr[c] = __float2bfloat16(v[i]);
    }
}

// ---------------- Fat GEMM dispatch: qkv (288 blocks) + bottleneck silu (16 blocks) ----------------
constexpr int NQB = (TD / 128) * (BL / 128);   // 288
constexpr int NFAT = NQB + BL / 128;           // 304
__global__ __launch_bounds__(512)
void fat_gemm_kernel(const __hip_bfloat16* __restrict__ A1,
                     const __hip_bfloat16* __restrict__ B1,
                     const float* __restrict__ bias1,
                     __hip_bfloat16* __restrict__ C1,
                     const __hip_bfloat16* __restrict__ A2,
                     const __hip_bfloat16* __restrict__ B2,
                     float* __restrict__ C2) {
    __shared__ short lds[2][2][128 * 64];
    int bid = blockIdx.x;
    bid = (bid & 7) * (NFAT / 8) + (bid >> 3);          // bijective: 304 % 8 == 0
    bool isq = bid < NQB;
    int bx, by, N;
    const __hip_bfloat16 *A, *BT;
    if (isq) { bx = bid % 18; by = bid / 18; A = A1; BT = B1; N = TD; }
    else     { int b2 = bid - NQB; bx = 0; by = b2; A = A2; BT = B2; N = Rc; }
    const int K = Dc;

    int tid = threadIdx.x;
    int wave = tid >> 6, lane = tid & 63;
    int l16 = lane & 15, l4 = lane >> 4;
    int m0 = by * 128, n0 = bx * 128;

    int ab = wave >> 2;
    int r_in = lane >> 3;
    int s_src = (lane & 7) ^ r_in;
    const __hip_bfloat16* gbase = ab ? (BT + (size_t)n0 * K) : (A + (size_t)m0 * K);
    const __hip_bfloat16* gsrc =
        gbase + (size_t)((wave & 3) * 32 + r_in) * K + s_src * 8;

    int wr = (wave >> 2) * 64, wc = (wave & 3) * 32;
    int xs = l16 & 7;

    f32x4 acc[4][2];
#pragma unroll
    for (int i = 0; i < 4; i++)
#pragma unroll
        for (int j = 0; j < 2; j++) acc[i][j] = f32x4{0.f, 0.f, 0.f, 0.f};

    auto stage = [&](int buf, int kt) {
        const __hip_bfloat16* g = gsrc + kt * 64;
        short* lb = &lds[buf][ab][(wave & 3) * 32 * 64];
#pragma unroll
        for (int i = 0; i < 4; i++)
            GLOAD_LDS16(g + (size_t)i * 8 * K, lb + i * 8 * 64);
    };
    auto compute = [&](int buf) {
        const short* As = &lds[buf][0][0];
        const short* Bs = &lds[buf][1][0];
#pragma unroll
        for (int kk = 0; kk < 2; kk++) {
            bf16x8 af[4], bfr[2];
            int slot = (kk * 4 + l4) ^ xs;
#pragma unroll
            for (int f = 0; f < 4; f++)
                af[f] = *reinterpret_cast<const bf16x8*>(
                    &As[(wr + f * 16 + l16) * 64 + slot * 8]);
#pragma unroll
            for (int f = 0; f < 2; f++)
                bfr[f] = *reinterpret_cast<const bf16x8*>(
                    &Bs[(wc + f * 16 + l16) * 64 + slot * 8]);
#pragma unroll
            for (int i = 0; i < 4; i++)
#pragma unroll
                for (int j = 0; j < 2; j++)
                    acc[i][j] = __builtin_amdgcn_mfma_f32_16x16x32_bf16(
                        af[i], bfr[j], acc[i][j], 0, 0, 0);
        }
    };

    int NT = K / 64;
    int cur = 0;
    stage(0, 0);
    __syncthreads();
    for (int t = 0; t < NT; t++) {
        if (t + 1 < NT) stage(cur ^ 1, t + 1);
        compute(cur);
        if (t + 1 < NT) { __syncthreads(); cur ^= 1; }
    }

    int crow = l4 * 4;
#pragma unroll
    for (int i = 0; i < 4; i++) {
#pragma unroll
        for (int j = 0; j < 2; j++) {
            int col = n0 + wc + j * 16 + l16;
            float bb = isq ? bias1[col] : 0.f;
#pragma unroll
            for (int r = 0; r < 4; r++) {
                int rowm = m0 + wr + i * 16 + crow + r;
                float v = acc[i][j][r] + bb;
                if (isq) {
                    C1[(size_t)rowm * N + col] = __float2bfloat16(v);
                } else {
                    v = v / (1.f + expf(-v));            // silu
                    C2[(size_t)rowm * N + col] = v;
                }
            }
        }
    }
}

// ---------------- proj GEMM: 64x64 tile, 4 waves, 384 blocks (occupancy) ----------------
__global__ __launch_bounds__(256)
void gemm64_kernel(const __hip_bfloat16* __restrict__ A,
                   const __hip_bfloat16* __restrict__ BT,
                   const float* __restrict__ bias,
                   float* __restrict__ C, int M, int N, int K, int nbx) {
    __shared__ short lds[2][128 * 64];   // rows 0-63 = A, 64-127 = B
    int nwg = gridDim.x;
    int bid = blockIdx.x;
    if ((nwg & 7) == 0) bid = (bid & 7) * (nwg >> 3) + (bid >> 3);
    int m0 = (bid / nbx) * 64, n0 = (bid % nbx) * 64;

    int tid = threadIdx.x;
    int wave = tid >> 6, lane = tid & 63;
    int l16 = lane & 15, l4 = lane >> 4;

    int r_in = lane >> 3;
    int s_src = (lane & 7) ^ r_in;
    const __hip_bfloat16* gsrc = (wave < 2)
        ? A  + (size_t)(m0 + wave * 32 + r_in) * K + s_src * 8
        : BT + (size_t)(n0 + (wave - 2) * 32 + r_in) * K + s_src * 8;

    int wr = (wave >> 1) * 32, wc = (wave & 1) * 32;
    int xs = l16 & 7;

    f32x4 acc[2][2];
#pragma unroll
    for (int i = 0; i < 2; i++)
#pragma unroll
        for (int j = 0; j < 2; j++) acc[i][j] = f32x4{0.f, 0.f, 0.f, 0.f};

    auto stage = [&](int buf, int kt) {
        const __hip_bfloat16* g = gsrc + kt * 64;
        short* lb = &lds[buf][wave * 32 * 64];
#pragma unroll
        for (int i = 0; i < 4; i++)
            GLOAD_LDS16(g + (size_t)i * 8 * K, lb + i * 8 * 64);
    };
    auto compute = [&](int buf) {
        const short* As = &lds[buf][0];
        const short* Bs = &lds[buf][64 * 64];
#pragma unroll
        for (int kk = 0; kk < 2; kk++) {
            bf16x8 af[2], bfr[2];
            int slot = (kk * 4 + l4) ^ xs;
#pragma unroll
            for (int f = 0; f < 2; f++) {
                af[f]  = *reinterpret_cast<const bf16x8*>(
                    &As[(wr + f * 16 + l16) * 64 + slot * 8]);
                bfr[f] = *reinterpret_cast<const bf16x8*>(
                    &Bs[(wc + f * 16 + l16) * 64 + slot * 8]);
            }
#pragma unroll
            for (int i = 0; i < 2; i++)
#pragma unroll
                for (int j = 0; j < 2; j++)
                    acc[i][j] = __builtin_amdgcn_mfma_f32_16x16x32_bf16(
                        af[i], bfr[j], acc[i][j], 0, 0, 0);
        }
    };

    int NT = K / 64;
    int cur = 0;
    stage(0, 0);
    __syncthreads();
    for (int t = 0; t < NT; t++) {
        if (t + 1 < NT) stage(cur ^ 1, t + 1);
        compute(cur);
        if (t + 1 < NT) { __syncthreads(); cur ^= 1; }
    }

    int crow = l4 * 4;
#pragma unroll
    for (int i = 0; i < 2; i++) {
#pragma unroll
        for (int j = 0; j < 2; j++) {
            int col = n0 + wc + j * 16 + l16;
            float bb = bias[col];
#pragma unroll
            for (int r = 0; r < 4; r++) {
                int rowm = m0 + wr + i * 16 + crow + r;
                C[(size_t)rowm * N + col] = acc[i][j][r] + bb;
            }
        }
    }
}

// ---------------- Phase A (MFMA): U_c^T = (K^T Vog)^T stored [e][d], zc via ones-row; fused gate ----------------
constexpr int LQ = 72;    // padded row stride (shorts) for 64-col bf16 tiles
__global__ __launch_bounds__(256)
void phaseA_kernel(const __hip_bfloat16* __restrict__ qkv, const float* __restrict__ tbuf,
                   const float* __restrict__ Wb2, const float* __restrict__ temperature,
                   float* __restrict__ gate_out,
                   float* __restrict__ SU, float* __restrict__ zc) {
    int bid = blockIdx.x;           // bh*16 + c
    int bh = bid >> 4, c = bid & 15;
    int b = bh / Hc, h = bh % Hc;
    int tok0 = b * Lc + c * CH;
    __shared__ short KsT[64 * LQ];  // [d][t]
    __shared__ short VT[80 * LQ];   // [e][t]; row 64 = ones (-> zc); 65..79 = 0
    __shared__ float w2s[5 * 128];  // Wb2 head slice, [c][r]
    __shared__ float ogs[64];
    int tid = threadIdx.x;
    int wave = tid >> 6, lane = tid & 63;
    int l16 = lane & 15, l4 = lane >> 4;

    // stage Wb2 head slice [c][r]
    for (int i = tid; i < 640; i += 256) {
        int cc = i >> 7, r = i & 127;
        w2s[i] = Wb2[r * (Hc * 5) + h * 5 + cc];
    }
    // load k/v into regs early (overlaps gate compute)
    bf16x8 k8[2], v8[2];
#pragma unroll
    for (int i = 0; i < 2; i++) {
        int c8 = tid + i * 256;
        int tt = c8 >> 3, d8 = (c8 & 7) * 8;
        size_t rowoff = (size_t)(tok0 + tt) * TD + h * dh;
        k8[i] = *reinterpret_cast<const bf16x8*>(qkv + rowoff + Dc + d8);
        v8[i] = *reinterpret_cast<const bf16x8*>(qkv + rowoff + 2 * Dc + d8);
    }
    // zero VT rows 64..79, then set ones row
    for (int i = tid; i < 16 * LQ; i += 256) VT[64 * LQ + i] = 0;
    if (tid < 64) VT[64 * LQ + tid] = f2b(1.0f);
    __syncthreads();   // w2s ready

    // gate: 4 lanes per token, 32 R-values each; shfl reduce
    {
        int tt = tid >> 2, sub = tid & 3;
        const float* tr = tbuf + (size_t)(tok0 + tt) * Rc + sub * 32;
        float p[5] = {};
        for (int r4 = 0; r4 < 32; r4 += 4) {
            float4 tv = *reinterpret_cast<const float4*>(tr + r4);
#pragma unroll
            for (int cc = 0; cc < 5; cc++) {
                float4 w4 = *reinterpret_cast<const float4*>(&w2s[cc * 128 + sub * 32 + r4]);
                p[cc] = fmaf(tv.x, w4.x, fmaf(tv.y, w4.y,
                        fmaf(tv.z, w4.z, fmaf(tv.w, w4.w, p[cc]))));
            }
        }
#pragma unroll
        for (int cc = 0; cc < 5; cc++) {
            p[cc] += __shfl_xor(p[cc], 1, 64);
            p[cc] += __shfl_xor(p[cc], 2, 64);
        }
        if (sub == 0) {
            const float PI = 3.14159265358979323846f;
            float sem_amp = 1.f / (1.f + expf(-p[0]));
            float sem_phase = tanhf(p[1]) * PI;
            float ctx_amp = 1.f / (1.f + expf(-p[2]));
            float ctx_phase = tanhf(p[3]) * PI;
            float temp = fminf(fmaxf(temperature[0], 0.1f), 2.0f);
            float inter = tanhf(sem_amp * ctx_amp * cosf(sem_phase - ctx_phase)) * temp;
            float g = 1.f / (1.f + expf(-inter));
            gate_out[(size_t)(tok0 + tt) * Hc + h] = g;
            ogs[tt] = 1.f + g;
        }
    }
    __syncthreads();   // ogs ready

    // transposed LDS writes: KsT[d][t], VT[e][t]
#pragma unroll
    for (int i = 0; i < 2; i++) {
        int c8 = tid + i * 256;
        int tt = c8 >> 3, d8 = (c8 & 7) * 8;
        float gv = ogs[tt];
#pragma unroll
        for (int j = 0; j < 8; j++) {
            float kv = bf2f(k8[i][j]);
            KsT[(d8 + j) * LQ + tt] = f2b(kv > 0.f ? kv + 1.f : expf(kv));
            VT[(d8 + j) * LQ + tt]  = f2b(bf2f(v8[i][j]) * gv);
        }
    }
    __syncthreads();

    // U[d][e] = sum_t K[t][d] * Vog[t][e]  (+ col e=64 -> zc[d])
    const short* arow = &KsT[(wave * 16 + l16) * LQ];
    f32x4 acc[5];
#pragma unroll
    for (int j = 0; j < 5; j++) acc[j] = f32x4{0.f, 0.f, 0.f, 0.f};
#pragma unroll
    for (int kk = 0; kk < 2; kk++) {
        bf16x8 af = *reinterpret_cast<const bf16x8*>(&arow[kk * 32 + l4 * 8]);
#pragma unroll
        for (int j = 0; j < 5; j++) {
            bf16x8 bfv = *reinterpret_cast<const bf16x8*>(
                &VT[(j * 16 + l16) * LQ + kk * 32 + l4 * 8]);
            acc[j] = __builtin_amdgcn_mfma_f32_16x16x32_bf16(af, bfv, acc[j], 0, 0, 0);
        }
    }
    int dbase = wave * 16 + l4 * 4;
    float* SUo = SU + (size_t)bid * 4096;
#pragma unroll
    for (int j = 0; j < 4; j++) {
        int e = j * 16 + l16;
#pragma unroll
        for (int r = 0; r < 4; r++)
            SUo[e * 64 + dbase + r] = acc[j][r];
    }
    if (l16 == 0) {
#pragma unroll
        for (int r = 0; r < 4; r++)
            zc[bid * 64 + dbase + r] = acc[4][r];
    }
}

// ---------------- Phase B: exclusive prefix over chunks (one thread per element) ----------------
__global__ __launch_bounds__(256)
void prefix_kernel(float* __restrict__ SU, float* __restrict__ zc) {
    int gid = blockIdx.x * 256 + threadIdx.x;
    if (gid < BH * 4096) {
        int bh = gid >> 12, i = gid & 4095;
        float* S = SU + (size_t)bh * NC * 4096 + i;
        float r[NC];
#pragma unroll
        for (int cc = 0; cc < NC; cc++) r[cc] = S[cc * 4096];
        float run = 0.f;
#pragma unroll
        for (int cc = 0; cc < NC; cc++) { float tv = r[cc]; S[cc * 4096] = run; run += tv; }
    } else {
        int g2 = gid - BH * 4096;
        if (g2 < BH * 64) {
            int bh = g2 >> 6, i = g2 & 63;
            float* z = zc + (size_t)bh * NC * 64 + i;
            float r[NC];
#pragma unroll
            for (int cc = 0; cc < NC; cc++) r[cc] = z[cc * 64];
            float run = 0.f;
#pragma unroll
            for (int cc = 0; cc < NC; cc++) { float tv = r[cc]; z[cc * 64] = run; run += tv; }
        }
    }
}

// ---------------- Phase C: MFMA per-chunk output + mini-LN, bf16 out ----------------
constexpr int LB = 136;   // padded row stride for 128-col bf16 B-tile
__global__ __launch_bounds__(256)
void phaseC_kernel(const __hip_bfloat16* __restrict__ qkv, const float* __restrict__ gate,
                   const float* __restrict__ SU, const float* __restrict__ zc,
                   const float* __restrict__ mn_w, const float* __restrict__ mn_b,
                   __hip_bfloat16* __restrict__ attn) {
    int bid = blockIdx.x;           // bh*16 + c
    int bh = bid >> 4;
    int b = bh / Hc, h = bh % Hc;
    int tok0 = b * Lc + (bid & 15) * CH;
    __shared__ short Qs[64 * LQ];   // q_f  [l][d]
    __shared__ short Ks[64 * LQ];   // k_f  [t][d]
    __shared__ short Ps[64 * LQ];   // masked P [l][t]
    __shared__ short Bst[80 * LB];  // rows e: [V^T*og | S^T]; row64 = [1 | z_start]; 65..79 = 0
    int tid = threadIdx.x;
    int wave = tid >> 6, lane = tid & 63;
    int l16 = lane & 15, l4 = lane >> 4;

    const float* SUp = SU + (size_t)bid * 4096;   // prefixed, [e][d]
    const float* zcp = zc + (size_t)bid * 64;     // prefixed z_start

#pragma unroll
    for (int i = 0; i < 2; i++) {
        int c8 = tid + i * 256;
        int tt = c8 >> 3, d8 = (c8 & 7) * 8;
        size_t rowoff = (size_t)(tok0 + tt) * TD + h * dh;
        bf16x8 q8 = *reinterpret_cast<const bf16x8*>(qkv + rowoff + d8);
        bf16x8 k8 = *reinterpret_cast<const bf16x8*>(qkv + rowoff + Dc + d8);
        bf16x8 v8 = *reinterpret_cast<const bf16x8*>(qkv + rowoff + 2 * Dc + d8);
        float gv = 1.f + gate[(size_t)(tok0 + tt) * Hc + h];
        short qo[8], ko[8];
#pragma unroll
        for (int j = 0; j < 8; j++) {
            float qv = bf2f(q8[j]);
            qo[j] = f2b(qv > 0.f ? qv + 1.f : expf(qv));
            float kv = bf2f(k8[j]);
            ko[j] = f2b(kv > 0.f ? kv + 1.f : expf(kv));
            Bst[(d8 + j) * LB + tt] = f2b(bf2f(v8[j]) * gv);   // V^T transpose write
        }
        *reinterpret_cast<bf16x8*>(&Qs[tt * LQ + d8]) = *reinterpret_cast<bf16x8*>(qo);
        *reinterpret_cast<bf16x8*>(&Ks[tt * LQ + d8]) = *reinterpret_cast<bf16x8*>(ko);
        float4 sa = *reinterpret_cast<const float4*>(SUp + tt * 64 + d8);
        float4 sb = *reinterpret_cast<const float4*>(SUp + tt * 64 + d8 + 4);
        short so[8] = { f2b(sa.x), f2b(sa.y), f2b(sa.z), f2b(sa.w),
                        f2b(sb.x), f2b(sb.y), f2b(sb.z), f2b(sb.w) };
        *reinterpret_cast<bf16x8*>(&Bst[tt * LB + 64 + d8]) = *reinterpret_cast<bf16x8*>(so);
    }
    if (tid < 64) {
        Bst[64 * LB + tid] = f2b(1.0f);          // ones -> row-sum of P (den part 1)
        Bst[64 * LB + 64 + tid] = f2b(zcp[tid]); // z_start -> q.z (den part 2)
    } else {
        for (int i2 = tid - 64; i2 < 15 * LB; i2 += 192) Bst[65 * LB + i2] = 0;
    }
    __syncthreads();   // barrier 1

    // ---- P = Qf Kf^T : wave owns l-strip [wave*16, wave*16+16) ----
    const short* arow = &Qs[(wave * 16 + l16) * LQ];
    f32x4 accp[4];
#pragma unroll
    for (int j = 0; j < 4; j++) accp[j] = f32x4{0.f, 0.f, 0.f, 0.f};
#pragma unroll
    for (int kk = 0; kk < 2; kk++) {
        bf16x8 af = *reinterpret_cast<const bf16x8*>(&arow[kk * 32 + l4 * 8]);
#pragma unroll
        for (int j = 0; j < 4; j++) {
            bf16x8 bfv = *reinterpret_cast<const bf16x8*>(
                &Ks[(j * 16 + l16) * LQ + kk * 32 + l4 * 8]);
            accp[j] = __builtin_amdgcn_mfma_f32_16x16x32_bf16(af, bfv, accp[j], 0, 0, 0);
        }
    }
#pragma unroll
    for (int j = 0; j < 4; j++) {
#pragma unroll
        for (int r = 0; r < 4; r++) {
            int l = wave * 16 + l4 * 4 + r;
            int t = j * 16 + l16;
            float pv = (t <= l) ? accp[j][r] : 0.f;
            Ps[l * LQ + t] = f2b(pv);
        }
    }
    __syncthreads();   // barrier 2

    // ---- O = [P | Qf] @ Bst^T : 5 e-tiles (j=4 col 64 = den) ----
    const short* prow = &Ps[(wave * 16 + l16) * LQ];
    f32x4 acc[5];
#pragma unroll
    for (int j = 0; j < 5; j++) acc[j] = f32x4{0.f, 0.f, 0.f, 0.f};
#pragma unroll
    for (int kk = 0; kk < 4; kk++) {
        bf16x8 af = (kk < 2)
            ? *reinterpret_cast<const bf16x8*>(&prow[kk * 32 + l4 * 8])
            : *reinterpret_cast<const bf16x8*>(&arow[(kk - 2) * 32 + l4 * 8]);
#pragma unroll
        for (int j = 0; j < 5; j++) {
            bf16x8 bfv = *reinterpret_cast<const bf16x8*>(
                &Bst[(j * 16 + l16) * LB + kk * 32 + l4 * 8]);
            acc[j] = __builtin_amdgcn_mfma_f32_16x16x32_bf16(af, bfv, acc[j], 0, 0, 0);
        }
    }

    // ---- epilogue: den, mini-LN over e (in-register, shfl over l16 group) ----
#pragma unroll
    for (int r = 0; r < 4; r++) {
        float den = __shfl(acc[4][r], l4 * 16) + 1e-6f;
        float inv = 1.f / den;
        float v0 = acc[0][r] * inv, v1 = acc[1][r] * inv;
        float v2 = acc[2][r] * inv, v3 = acc[3][r] * inv;
        float s1 = v0 + v1 + v2 + v3;
        float s2 = v0 * v0 + v1 * v1 + v2 * v2 + v3 * v3;
#pragma unroll
        for (int m = 1; m < 16; m <<= 1) {
            s1 += __shfl_xor(s1, m, 64);
            s2 += __shfl_xor(s2, m, 64);
        }
        float mu = s1 * (1.f / 64.f);
        float rstd = rsqrtf(s2 * (1.f / 64.f) - mu * mu + 1e-5f);
        int l = wave * 16 + l4 * 4 + r;
        __hip_bfloat16* orow = attn + (size_t)(tok0 + l) * Dc + h * dh;
        float vj[4] = {v0, v1, v2, v3};
#pragma unroll
        for (int j = 0; j < 4; j++) {
            int e = j * 16 + l16;
            orow[e] = __float2bfloat16((vj[j] - mu) * rstd * mn_w[e] + mn_b[e]);
        }
    }
}

extern "C" void kernel_launch(void* const* d_in, const int* in_sizes, int n_in,
                              void* d_out, int out_size, void* d_ws, size_t ws_size,
                              hipStream_t stream) {
    const float* x     = (const float*)d_in[0];
    const float* Wqkv  = (const float*)d_in[1];
    const float* bqkv  = (const float*)d_in[2];
    const float* Wb1   = (const float*)d_in[3];
    const float* Wb2   = (const float*)d_in[4];
    const float* temp  = (const float*)d_in[5];
    const float* Wproj = (const float*)d_in[6];
    const float* bproj = (const float*)d_in[7];
    const float* ln_w  = (const float*)d_in[8];
    const float* ln_b  = (const float*)d_in[9];
    const float* mn_w  = (const float*)d_in[10];
    const float* mn_b  = (const float*)d_in[11];

    float* out0 = (float*)d_out;                 // [2048, 768]
    float* gate = out0 + (size_t)BL * Dc;        // [2048, 12]

    float* ws   = (float*)d_ws;
    float* tbuf = ws;                            // 2048*128 f32
    float* SU   = tbuf + (size_t)BL * Rc;        // 24*16*4096 f32 (U^T, [e][d])
    float* zc   = SU + (size_t)BH * NC * 4096;   // 24*16*64 f32
    __hip_bfloat16* bfr = (__hip_bfloat16*)(zc + (size_t)BH * NC * 64);
    __hip_bfloat16* qkvb   = bfr;                        // 2048*2304 bf16
    __hip_bfloat16* xnb    = qkvb + (size_t)BL * TD;     // 2048*768 bf16
    __hip_bfloat16* xb     = xnb + (size_t)BL * Dc;      // 2048*768 bf16 (raw x)
    __hip_bfloat16* attnb  = xb + (size_t)BL * Dc;       // 2048*768 bf16
    __hip_bfloat16* WqkvT  = attnb + (size_t)BL * Dc;    // 2304*768 bf16
    __hip_bfloat16* WprojT = WqkvT + (size_t)TD * Dc;    // 768*768 bf16
    __hip_bfloat16* Wb1T   = WprojT + (size_t)Dc * Dc;   // 128*768 bf16

    // 1. prep: weight transposes + LayerNorm
    prep_kernel<<<NPREP, 256, 0, stream>>>(x, ln_w, ln_b, Wqkv, Wproj, Wb1,
                                           xnb, xb, WqkvT, WprojT, Wb1T);
    // 2. fat dispatch: qkv GEMM (bf16 out) + bottleneck silu GEMM (fp32 out)
    fat_gemm_kernel<<<NFAT, 512, 0, stream>>>(xnb, WqkvT, bqkv, qkvb, xb, Wb1T, tbuf);
    // 3. phaseA (MFMA): per-chunk U^T + z sums + fused gate
    phaseA_kernel<<<BH * NC, 256, 0, stream>>>(qkvb, tbuf, Wb2, temp, gate, SU, zc);
    // 4. exclusive prefix over chunks
    prefix_kernel<<<(BH * 4096 + BH * 64 + 255) / 256, 256, 0, stream>>>(SU, zc);
    // 5. per-chunk outputs (MFMA) + mini-LN -> bf16
    phaseC_kernel<<<BH * NC, 256, 0, stream>>>(qkvb, gate, SU, zc, mn_w, mn_b, attnb);
    // 6. out0 = attn @ Wproj + bproj  (64x64-tile MFMA, 384 blocks)
    gemm64_kernel<<<(BL / 64) * (Dc / 64), 256, 0, stream>>>(
        attnb, WprojT, bproj, out0, BL, Dc, Dc, Dc / 64);
}